// Round 24
// baseline (2739.932 us; speedup 1.0000x reference)
//
#include <hip/hip_runtime.h>
#include <math.h>

typedef unsigned int u32;
typedef unsigned long long u64;

#define STRIDE 262656          // per-column stride in floats
#define KSHIFT 15
#define KROUND 0x4000u
#define BAND   6144            // 24 exponents x 256 mantissa steps per sign
#define NB     12288           // bins per column
#define PA17   0x7100u
#define NA17   0x17700u
#define NCOLS  16
#define ZW     (NB*NCOLS)      // u32 words in one bin buffer
#define ACT_PRELU 0
#define ACT_RELU  1
#define ACT_ELU   2

__device__ __forceinline__ float k2f(u32 k){
    u32 u = (k & 0x80000000u) ? k : (k ^ 0x7FFFFFFFu);
    return __uint_as_float(u);
}
__device__ __forceinline__ int bin_of(float v){
    float av = fabsf(v);
    av = fminf(fmaxf(av, 0.00390625f), 65535.96875f);
    u32 u = __float_as_uint(av);
    if (v < 0.f){
        u32 k = 0x80000000u | u;
        int b = (int)(((k + KROUND) >> KSHIFT) - NA17);
        b = b < 0 ? 0 : (b > BAND-1 ? BAND-1 : b);
        return BAND + b;
    } else {
        u32 k = u ^ 0x7FFFFFFFu;
        int b = (int)(((k + KROUND) >> KSHIFT) - PA17);
        b = b < 0 ? 0 : (b > BAND-1 ? BAND-1 : b);
        return b;
    }
}
__device__ __forceinline__ float bin_val(int bin){
    u32 k17 = (bin < BAND) ? ((u32)bin + PA17) : ((u32)(bin - BAND) + NA17);
    return k2f(k17 << KSHIFT);
}
__device__ __forceinline__ float actf(int act, float alpha, float v){
    if (act == ACT_PRELU) return (v >= 0.f) ? v : alpha * v;
    if (act == ACT_RELU)  return (v > 0.f) ? v : 0.f;
    return (v > 0.f) ? v : expm1f(v);
}

// wave run-length dedup -> one GLOBAL atomic per run per wave
__device__ __forceinline__ void hist_add(u32* __restrict__ Hc, int bin, bool valid, int lane){
    u32 bn = valid ? (u32)bin : 0xFFFFFFFFu;
    u32 prev = __shfl_up(bn, 1);
    bool diff = (lane == 0) || (prev != bn);
    u64 m = __ballot(diff || !valid);
    if (valid && diff){
        u64 above = m & ~((2ull << lane) - 1ull);
        int nxt = above ? (__ffsll((unsigned long long)above) - 1) : 64;
        atomicAdd(&Hc[bin], (u32)(nxt - lane));
    }
}

// wave run-length dedup -> one packed-u16 LDS atomic per run per wave
__device__ __forceinline__ void lds_hist_dedup(u32* __restrict__ hist, int bin, bool valid, int lane){
    u32 bn = valid ? (u32)bin : 0xFFFFFFFFu;
    u32 prev = __shfl_up(bn, 1);
    bool diff = (lane == 0) || (prev != bn);
    u64 m = __ballot(diff || !valid);
    if (valid && diff){
        u64 above = m & ~((2ull << lane) - 1ull);
        int nxt = above ? (__ffsll((unsigned long long)above) - 1) : 64;
        u32 cnt = (u32)(nxt - lane);
        atomicAdd(&hist[bin >> 1], cnt << ((bin & 1) * 16));
    }
}

// ---------------- fold+transpose x -> fx[8][STRIDE]; also zero bin0 ----------------
__global__ __launch_bounds__(256) void foldx(const float* __restrict__ x, float* __restrict__ fx,
                                             uint4* __restrict__ zb)
{
    __shared__ float4 tile[1024];    // 256 rows x 16 floats
    const int tid = threadIdx.x;
    const int h0 = blockIdx.x * 256;
    for (int i = tid; i < 1024; i += 256) tile[i] = ((const float4*)x)[(size_t)h0*4 + i];
    __syncthreads();
    float4 a = tile[tid*4+0], b = tile[tid*4+1], c = tile[tid*4+2], d = tile[tid*4+3];
    const int h = h0 + tid;
    fx[(size_t)0*STRIDE + h] = a.x + a.y;
    fx[(size_t)1*STRIDE + h] = a.z + a.w;
    fx[(size_t)2*STRIDE + h] = b.x + b.y;
    fx[(size_t)3*STRIDE + h] = b.z + b.w;
    fx[(size_t)4*STRIDE + h] = c.x + c.y;
    fx[(size_t)5*STRIDE + h] = c.z + c.w;
    fx[(size_t)6*STRIDE + h] = d.x + d.y;
    fx[(size_t)7*STRIDE + h] = d.z + d.w;
    const uint4 z = make_uint4(0,0,0,0);
    for (int i = blockIdx.x*256 + tid; i < ZW/4; i += gridDim.x*256) zb[i] = z;
}

// ---------------- layer-0 conv+hist: float4 shifted window, 4 outputs/thread ----------------
#define C0CHUNK 8192
__global__ __launch_bounds__(512) void conv0_lds(const float* __restrict__ fx, u32* __restrict__ H,
                                                 const float* __restrict__ w0, const float* __restrict__ b0)
{
    __shared__ u32 hist[NB/2];                 // 24 KB packed u16 pairs
    __shared__ __align__(16) float s0f[2148];
    __shared__ float sw[100];                  // sw[99] = 0 pad
    const int colv = blockIdx.y;               // 0..15 = o*8 + wp
    const int o = colv >> 3, wp = colv & 7;
    const int tid = threadIdx.x;
    const int p0 = blockIdx.x * C0CHUNK;
    const int p1 = min(p0 + C0CHUNK, 262242);
    if (p0 >= 262242) return;
    for (int i = tid; i < NB/2; i += 512) hist[i] = 0;
    if (tid < 99) sw[tid] = w0[o*99 + tid];
    if (tid == 99) sw[99] = 0.f;
    const float bias = 2.f * b0[o];            // fold doubles bias
    __syncthreads();
    const float* fc = fx + (size_t)wp * STRIDE;
    const float4* s4 = (const float4*)s0f;
    for (int t0 = p0; t0 < p1; t0 += 2048){
        for (int i = tid; i < 2148; i += 512){
            int h = t0 - 98 + i;
            s0f[i] = (h >= 0 && h < 262144) ? fc[h] : 0.f;
        }
        __syncthreads();
        float a0 = bias, a1 = bias, a2 = bias, a3 = bias;
        float4 c = s4[tid];
        #pragma unroll
        for (int jb = 0; jb < 25; jb++){
            float4 n = s4[tid + jb + 1];
            float w0_ = sw[4*jb+0], w1_ = sw[4*jb+1], w2_ = sw[4*jb+2], w3_ = sw[4*jb+3];
            a0 += w0_*c.x; a1 += w0_*c.y; a2 += w0_*c.z; a3 += w0_*c.w;
            a0 += w1_*c.y; a1 += w1_*c.z; a2 += w1_*c.w; a3 += w1_*n.x;
            a0 += w2_*c.z; a1 += w2_*c.w; a2 += w2_*n.x; a3 += w2_*n.y;
            a0 += w3_*c.w; a1 += w3_*n.x; a2 += w3_*n.y; a3 += w3_*n.z;   // sw[99]=0
            c = n;
        }
        int hp = t0 + tid*4;
        if (hp     < p1){ int b = bin_of(a0); atomicAdd(&hist[b>>1], 1u << ((b&1)*16)); }
        if (hp + 1 < p1){ int b = bin_of(a1); atomicAdd(&hist[b>>1], 1u << ((b&1)*16)); }
        if (hp + 2 < p1){ int b = bin_of(a2); atomicAdd(&hist[b>>1], 1u << ((b&1)*16)); }
        if (hp + 3 < p1){ int b = bin_of(a3); atomicAdd(&hist[b>>1], 1u << ((b&1)*16)); }
        __syncthreads();
    }
    u32* Hc = H + (size_t)colv * NB;
    for (int i = tid; i < NB/2; i += 512){
        u32 w = hist[i];
        if (w){
            u32 lo = w & 0xFFFFu, hi = w >> 16;
            if (lo) atomicAdd(&Hc[2*i],   lo);
            if (hi) atomicAdd(&Hc[2*i+1], hi);
        }
    }
}

// ---------------- run-walk K=9 conv+hist for layers 1..17 (reads PREFIX, not vals) ----------------
#define C9CHUNK 8192
__global__ __launch_bounds__(512) void runconv9(
    const u32* __restrict__ P, u32* __restrict__ H,
    const float* __restrict__ Wt, const float* __restrict__ Bs,
    int Hin, int Hout, float bscale, int pact, const float* __restrict__ pAlpha, int pshift)
{
    __shared__ u32 hist[NB/2];       // 24 KB
    const int colv = blockIdx.y;     // o*8 + wp
    const int o = colv >> 3, wp = colv & 7;
    const int tid = threadIdx.x;
    const int lane = tid & 63;
    const int p0 = blockIdx.x * C9CHUNK;
    const int p1 = min(p0 + C9CHUNK, Hout);
    if (p0 >= Hout) return;
    for (int i = tid; i < NB/2; i += 512) hist[i] = 0;
    float w0r[9], w1r[9];
    #pragma unroll
    for (int j = 0; j < 9; j++){ w0r[j] = Wt[(o*2)*9 + j]; w1r[j] = Wt[(o*2)*9 + 9 + j]; }
    const float bv = bscale * Bs[o];
    const float pal = pAlpha[0];
    __syncthreads();
    const u32* P0 = P + (size_t)(0*8 + wp)*NB;
    const u32* P1 = P + (size_t)(1*8 + wp)*NB;
    const int start = p0 + tid*16;

    int b0, b1i; u32 e0, e1; float v0c, v1c;
    {
        int rr = start - 8; if (rr < 0) rr = 0; if (rr >= Hin) rr = Hin - 1;
        u32 r = (u32)(rr >> pshift);
        int lo = 0, hi = NB - 1;
        while (lo < hi){ int m = (lo+hi)>>1; if (P0[m] > r) hi = m; else lo = m + 1; }
        b0 = lo; e0 = P0[lo]; v0c = actf(pact, pal, bin_val(lo));
        lo = 0; hi = NB - 1;
        while (lo < hi){ int m = (lo+hi)>>1; if (P1[m] > r) hi = m; else lo = m + 1; }
        b1i = lo; e1 = P1[lo]; v1c = actf(pact, pal, bin_val(lo));
    }
    float win0[8], win1[8];
    #pragma unroll
    for (int k = 0; k < 8; k++){
        int h = start - 8 + k;
        float v0 = 0.f, v1 = 0.f;
        if (h >= 0 && h < Hin){
            u32 r = (u32)(h >> pshift);
            while (e0 <= r){ ++b0; e0 = P0[b0]; v0c = actf(pact, pal, bin_val(b0)); }
            while (e1 <= r){ ++b1i; e1 = P1[b1i]; v1c = actf(pact, pal, bin_val(b1i)); }
            v0 = v0c; v1 = v1c;
        }
        win0[k] = v0; win1[k] = v1;
    }
    #pragma unroll
    for (int q = 0; q < 16; q++){
        int hp = start + q;
        float nv0 = 0.f, nv1 = 0.f;
        if (hp < Hin){
            u32 r = (u32)(hp >> pshift);
            while (e0 <= r){ ++b0; e0 = P0[b0]; v0c = actf(pact, pal, bin_val(b0)); }
            while (e1 <= r){ ++b1i; e1 = P1[b1i]; v1c = actf(pact, pal, bin_val(b1i)); }
            nv0 = v0c; nv1 = v1c;
        }
        float a = bv;
        a += w0r[0]*win0[0]; a += w0r[1]*win0[1]; a += w0r[2]*win0[2]; a += w0r[3]*win0[3];
        a += w0r[4]*win0[4]; a += w0r[5]*win0[5]; a += w0r[6]*win0[6]; a += w0r[7]*win0[7];
        a += w0r[8]*nv0;
        a += w1r[0]*win1[0]; a += w1r[1]*win1[1]; a += w1r[2]*win1[2]; a += w1r[3]*win1[3];
        a += w1r[4]*win1[4]; a += w1r[5]*win1[5]; a += w1r[6]*win1[6]; a += w1r[7]*win1[7];
        a += w1r[8]*nv1;
        bool valid = (hp < p1) && (start < p1);
        lds_hist_dedup(hist, bin_of(a), valid, lane);
        #pragma unroll
        for (int k = 0; k < 7; k++){ win0[k] = win0[k+1]; win1[k] = win1[k+1]; }
        win0[7] = nv0; win1[7] = nv1;
    }
    __syncthreads();
    u32* Hc = H + (size_t)colv * NB;
    for (int i = tid; i < NB/2; i += 512){
        u32 w = hist[i];
        if (w){
            u32 lo = w & 0xFFFFu, hi = w >> 16;
            if (lo) atomicAdd(&Hc[2*i],   lo);
            if (hi) atomicAdd(&Hc[2*i+1], hi);
        }
    }
}

// ---------------- K=9 conv+hist (layer 18, folded input; reads vals) ----------------
template<int FOLDIN>
__global__ __launch_bounds__(512) void conv9_lds(
    const float* __restrict__ In, u32* __restrict__ H,
    const float* __restrict__ Wt, const float* __restrict__ Bs,
    int Hin, int Hout, int Wi, int Wo, float bscale)
{
    __shared__ u32 hist[NB/2];                 // 24 KB
    __shared__ __align__(16) float s0f[2056];
    __shared__ __align__(16) float s1f[2056];
    const int colv = blockIdx.y;               // o*Wo + wp
    const int o = colv / Wo, wp = colv % Wo;
    const int tid = threadIdx.x;
    const int lane = tid & 63;
    const int p0 = blockIdx.x * C9CHUNK;
    const int p1 = min(p0 + C9CHUNK, Hout);
    if (p0 >= Hout) return;
    for (int i = tid; i < NB/2; i += 512) hist[i] = 0;
    float w0r[9], w1r[9];
    #pragma unroll
    for (int j = 0; j < 9; j++){ w0r[j] = Wt[(o*2)*9 + j]; w1r[j] = Wt[(o*2)*9 + 9 + j]; }
    const float bv = bscale * Bs[o];
    __syncthreads();
    const float* i00 = In + (size_t)(0*Wi + (FOLDIN ? 2*wp   : wp))*STRIDE;
    const float* i01 = In + (size_t)(0*Wi + (FOLDIN ? 2*wp+1 : wp))*STRIDE;
    const float* i10 = In + (size_t)(1*Wi + (FOLDIN ? 2*wp   : wp))*STRIDE;
    const float* i11 = In + (size_t)(1*Wi + (FOLDIN ? 2*wp+1 : wp))*STRIDE;
    const float4* s40 = (const float4*)s0f;
    const float4* s41 = (const float4*)s1f;
    for (int t0 = p0; t0 < p1; t0 += 2048){
        for (int i = tid; i < 2056; i += 512){
            int h = t0 - 8 + i;
            float v0 = 0.f, v1 = 0.f;
            if (h >= 0 && h < Hin){
                v0 = FOLDIN ? (i00[h] + i01[h]) : i00[h];
                v1 = FOLDIN ? (i10[h] + i11[h]) : i10[h];
            }
            s0f[i] = v0; s1f[i] = v1;
        }
        __syncthreads();
        float a0 = bv, a1 = bv, a2 = bv, a3 = bv;
        {
            float4 X = s40[tid], Y = s40[tid+1], Z = s40[tid+2];
            a0 += w0r[0]*X.x; a1 += w0r[0]*X.y; a2 += w0r[0]*X.z; a3 += w0r[0]*X.w;
            a0 += w0r[1]*X.y; a1 += w0r[1]*X.z; a2 += w0r[1]*X.w; a3 += w0r[1]*Y.x;
            a0 += w0r[2]*X.z; a1 += w0r[2]*X.w; a2 += w0r[2]*Y.x; a3 += w0r[2]*Y.y;
            a0 += w0r[3]*X.w; a1 += w0r[3]*Y.x; a2 += w0r[3]*Y.y; a3 += w0r[3]*Y.z;
            a0 += w0r[4]*Y.x; a1 += w0r[4]*Y.y; a2 += w0r[4]*Y.z; a3 += w0r[4]*Y.w;
            a0 += w0r[5]*Y.y; a1 += w0r[5]*Y.z; a2 += w0r[5]*Y.w; a3 += w0r[5]*Z.x;
            a0 += w0r[6]*Y.z; a1 += w0r[6]*Y.w; a2 += w0r[6]*Z.x; a3 += w0r[6]*Z.y;
            a0 += w0r[7]*Y.w; a1 += w0r[7]*Z.x; a2 += w0r[7]*Z.y; a3 += w0r[7]*Z.z;
            a0 += w0r[8]*Z.x; a1 += w0r[8]*Z.y; a2 += w0r[8]*Z.z; a3 += w0r[8]*Z.w;
        }
        {
            float4 X = s41[tid], Y = s41[tid+1], Z = s41[tid+2];
            a0 += w1r[0]*X.x; a1 += w1r[0]*X.y; a2 += w1r[0]*X.z; a3 += w1r[0]*X.w;
            a0 += w1r[1]*X.y; a1 += w1r[1]*X.z; a2 += w1r[1]*X.w; a3 += w1r[1]*Y.x;
            a0 += w1r[2]*X.z; a1 += w1r[2]*X.w; a2 += w1r[2]*Y.x; a3 += w1r[2]*Y.y;
            a0 += w1r[3]*X.w; a1 += w1r[3]*Y.x; a2 += w1r[3]*Y.y; a3 += w1r[3]*Y.z;
            a0 += w1r[4]*Y.x; a1 += w1r[4]*Y.y; a2 += w1r[4]*Y.z; a3 += w1r[4]*Y.w;
            a0 += w1r[5]*Y.y; a1 += w1r[5]*Y.z; a2 += w1r[5]*Y.w; a3 += w1r[5]*Z.x;
            a0 += w1r[6]*Y.z; a1 += w1r[6]*Y.w; a2 += w1r[6]*Z.x; a3 += w1r[6]*Z.y;
            a0 += w1r[7]*Y.w; a1 += w1r[7]*Z.x; a2 += w1r[7]*Z.y; a3 += w1r[7]*Z.z;
            a0 += w1r[8]*Z.x; a1 += w1r[8]*Z.y; a2 += w1r[8]*Z.z; a3 += w1r[8]*Z.w;
        }
        int hp = t0 + tid*4;
        lds_hist_dedup(hist, bin_of(a0), hp     < p1, lane);
        lds_hist_dedup(hist, bin_of(a1), hp + 1 < p1, lane);
        lds_hist_dedup(hist, bin_of(a2), hp + 2 < p1, lane);
        lds_hist_dedup(hist, bin_of(a3), hp + 3 < p1, lane);
        __syncthreads();
    }
    u32* Hc = H + (size_t)colv * NB;
    for (int i = tid; i < NB/2; i += 512){
        u32 w = hist[i];
        if (w){
            u32 lo = w & 0xFFFFu, hi = w >> 16;
            if (lo) atomicAdd(&Hc[2*i],   lo);
            if (hi) atomicAdd(&Hc[2*i+1], hi);
        }
    }
}

// ---------------- layer-19 conv+hist (K=358, 2->5ch; global dedup atomics) ----------------
template<int INC, int OUTC>
__global__ __launch_bounds__(256) void conv_hist_t(
    const float* __restrict__ In, u32* __restrict__ H,
    const float* __restrict__ Wt, const float* __restrict__ Bs,
    int Hin, int Hout, int K, int pad, int Wi, int Wo, int foldIn, float bscale)
{
    __shared__ float sIn[INC][613];
    __shared__ float sW[OUTC*INC*358];
    const int wp = blockIdx.y;
    const int h0 = blockIdx.x * 256;
    const int tid = threadIdx.x;
    const int lane = tid & 63;
    const int tl = 256 + K - 1;
    for (int t = tid; t < INC*tl; t += 256){
        int c = t / tl, r = t - c*tl;
        int h = h0 - pad + r;
        float v = 0.f;
        if (h >= 0 && h < Hin){
            if (foldIn) v = In[(size_t)(c*Wi + 2*wp)*STRIDE + h] + In[(size_t)(c*Wi + 2*wp + 1)*STRIDE + h];
            else        v = In[(size_t)(c*Wi + wp)*STRIDE + h];
        }
        sIn[c][r] = v;
    }
    for (int t = tid; t < OUTC*INC*K; t += 256) sW[t] = Wt[t];
    __syncthreads();
    int hp = h0 + tid;
    bool valid = (hp < Hout);
    float acc[OUTC];
    #pragma unroll
    for (int o = 0; o < OUTC; o++) acc[o] = bscale * Bs[o];
    for (int c = 0; c < INC; c++){
        for (int j = 0; j < K; j++){
            float xv = sIn[c][tid + j];
            #pragma unroll
            for (int o = 0; o < OUTC; o++) acc[o] += sW[(o*INC + c)*K + j] * xv;
        }
    }
    #pragma unroll
    for (int o = 0; o < OUTC; o++)
        hist_add(H + (size_t)(o*Wo + wp)*NB, bin_of(acc[o]), valid, lane);
}

// ---------------- fused scan (+optional prefix write, +optional fill) + next-bin zeroing ----------------
__global__ __launch_bounds__(1024) void scan_fill(
    const u32* __restrict__ H, float* __restrict__ dst, const float* __restrict__ alphaPtr,
    int kOut, int dup, int act, int fill, int pref, u32* __restrict__ prefOut,
    uint4* __restrict__ zb)
{
    __shared__ u32 pre[NB];          // 48 KB inclusive prefix
    __shared__ u32 warr[16];
    const int col = blockIdx.y;
    const int tid = threadIdx.x;
    const int lane = tid & 63, wv = tid >> 6;
    const u32* Hc = H + (size_t)col * NB;
    for (int i = tid; i < NB; i += 1024) pre[i] = Hc[i];
    __syncthreads();
    const int base = tid * 12;
    u32 v[12]; u32 s = 0;
    #pragma unroll
    for (int i = 0; i < 12; i++){ v[i] = pre[base + i]; s += v[i]; v[i] = s; }
    u32 ss = s;
    #pragma unroll
    for (int d = 1; d < 64; d <<= 1){
        u32 t = __shfl_up(ss, d);
        if (lane >= d) ss += t;
    }
    if (lane == 63) warr[wv] = ss;
    __syncthreads();
    u32 wb = 0;
    #pragma unroll
    for (int w = 0; w < 16; w++) wb += (w < wv) ? warr[w] : 0u;
    u32 excl = wb + ss - s;
    #pragma unroll
    for (int i = 0; i < 12; i++) pre[base + i] = v[i] + excl;
    __syncthreads();

    if (pref && blockIdx.x == 0){
        u32* po = prefOut + (size_t)col * NB;
        for (int i = tid; i < NB; i += 1024) po[i] = pre[i];
    }
    if (fill){
        const int S  = gridDim.x;
        const int nr = kOut / dup;
        const int per = (nr + S*1024 - 1) / (S*1024);
        int i = (blockIdx.x*1024 + tid) * per;
        const int i1 = min(i + per, nr);
        float* d = dst + (size_t)col * STRIDE;
        const float alpha = alphaPtr[0];
        int lo0 = 0;
        while (i < i1){
            int lo = lo0, hi = NB - 1;
            while (lo < hi){ int m = (lo + hi) >> 1; if (pre[m] > (u32)i) hi = m; else lo = m + 1; }
            float vv = bin_val(lo);
            if (act == ACT_PRELU)      vv = (vv >= 0.f) ? vv : alpha * vv;
            else if (act == ACT_RELU)  vv = (vv > 0.f) ? vv : 0.f;
            else                       vv = (vv > 0.f) ? vv : expm1f(vv);
            int e = (int)min((u32)i1, pre[lo]);
            for (; i < e; i++){
                int bse = i * dup;
                for (int dd = 0; dd < dup; dd++) d[bse + dd] = vv;
            }
            lo0 = lo + 1;
        }
    }
    // zero the other bin buffer for the next layer (vectorized)
    const uint4 z = make_uint4(0,0,0,0);
    int lin = (blockIdx.y * gridDim.x + blockIdx.x) * 1024 + tid;
    int tot = gridDim.x * gridDim.y * 1024;
    for (int q = lin; q < ZW/4; q += tot) zb[q] = z;
}

// ---------------- FC: 1000 logits, one block each; then log_softmax ----------------
__global__ __launch_bounds__(256) void fc_dot(const float* __restrict__ A, const float* __restrict__ Wfc,
                                              const float* __restrict__ bfc, float* __restrict__ logits)
{
    const int t = blockIdx.x;            // 0..999
    const int o = t / 200, j = t - o*200;
    const float* wrow = Wfc + (size_t)j*1600;
    float acc = 0.f;
    for (int q = threadIdx.x; q < 1600; q += 256){
        int p = q >> 1, wq = q & 1;
        acc += wrow[q] * A[(size_t)(o*2 + wq)*STRIDE + p];
    }
    __shared__ float red[256];
    red[threadIdx.x] = acc;
    __syncthreads();
    for (int s = 128; s > 0; s >>= 1){
        if (threadIdx.x < s) red[threadIdx.x] += red[threadIdx.x + s];
        __syncthreads();
    }
    if (threadIdx.x == 0) logits[t] = red[0] + bfc[j];
}

__global__ __launch_bounds__(1024) void lsm(const float* __restrict__ logits, float* __restrict__ out)
{
    const int tid = threadIdx.x;
    __shared__ float red[1024];
    float lg = (tid < 1000) ? logits[tid] : -INFINITY;
    red[tid] = lg;
    __syncthreads();
    for (int s = 512; s > 0; s >>= 1){
        if (tid < s) red[tid] = fmaxf(red[tid], red[tid + s]);
        __syncthreads();
    }
    float m = red[0];
    __syncthreads();
    red[tid] = (tid < 1000) ? expf(lg - m) : 0.f;
    __syncthreads();
    for (int s = 512; s > 0; s >>= 1){
        if (tid < s) red[tid] += red[tid + s];
        __syncthreads();
    }
    float lse = logf(red[0]);
    if (tid < 1000) out[tid] = lg - m - lse;
}

extern "C" void kernel_launch(void* const* d_in, const int* in_sizes, int n_in,
                              void* d_out, int out_size, void* d_ws, size_t ws_size,
                              hipStream_t stream)
{
    (void)in_sizes; (void)n_in; (void)out_size;
    const size_t need = (size_t)24*STRIDE*4 + (size_t)3*ZW*4 + 8192;
    if (ws_size < need) return;

    const float* x   = (const float*)d_in[0];
    const float* w0  = (const float*)d_in[1];
    const float* b0  = (const float*)d_in[2];
    const float* wm  = (const float*)d_in[3];
    const float* bm  = (const float*)d_in[4];
    const float* w18 = (const float*)d_in[5];
    const float* b18 = (const float*)d_in[6];
    const float* w19 = (const float*)d_in[7];
    const float* b19 = (const float*)d_in[8];
    const float* a1  = (const float*)d_in[9];
    const float* a2  = (const float*)d_in[10];
    const float* Wfc = (const float*)d_in[11];
    const float* bfc = (const float*)d_in[12];

    float* b1   = (float*)d_ws;
    float* fx   = b1 + (size_t)16*STRIDE;
    u32*  bin0  = (u32*)(fx + (size_t)8*STRIDE);
    u32*  bin1  = bin0 + (size_t)ZW;
    u32*  preG  = bin1 + (size_t)ZW;
    float* logits = (float*)(preG + (size_t)ZW);

    u32* cur = bin0;
    u32* nxt = bin1;

    // fold+transpose x; zero bin0
    foldx<<<1024, 256, 0, stream>>>(x, fx, (uint4*)cur);

    // ---- layer 0: conv(99) -> fold -> kmax 262144 -> PReLU(a1); prefix only ----
    conv0_lds<<<dim3(33, 16), 512, 0, stream>>>(fx, cur, w0, b0);
    scan_fill<<<dim3(16, 16), 1024, 0, stream>>>(cur, b1, a1, 262144, 2, ACT_PRELU,
                                                 0, 1, preG, (uint4*)nxt);
    { u32* t = cur; cur = nxt; nxt = t; }
    int Hin = 262144;

    // ---- layers 1..17: run-walk conv(9) -> kmax; prefix-only except L17 (fills for L18) ----
    static const int ks[17] = {249036,235929,222822,209715,196608,183500,170393,157286,
                               144179,131072,117964,104857,91750,78643,65536,52428,39321};
    for (int i = 0; i < 17; i++){
        int Hout = Hin + 8;
        int nch = (Hout + C9CHUNK - 1) / C9CHUNK;
        int pact = (i == 0) ? ACT_PRELU : (i == 1) ? ACT_PRELU : ACT_RELU;
        const float* palpha = (i == 0) ? a1 : a2;
        int pshift = (i == 0) ? 1 : 0;   // L0 output was dup=2
        runconv9<<<dim3(nch, 16), 512, 0, stream>>>(
            preG, cur, wm + (size_t)i*36, bm + (size_t)i*2, Hin, Hout, 1.f, pact, palpha, pshift);
        int isLast = (i == 16);
        scan_fill<<<dim3(16, 16), 1024, 0, stream>>>(cur, b1, a2, ks[i], 1,
                                                     (i == 0) ? ACT_PRELU : ACT_RELU,
                                                     isLast ? 1 : 0, isLast ? 0 : 1, preG, (uint4*)nxt);
        { u32* t = cur; cur = nxt; nxt = t; }
        Hin = ks[i];
    }

    // ---- layer 18: conv(9) folded widths 8->4 (reads vals) -> kmax 26214 -> ELU ----
    {
        int Hout = Hin + 8;   // 39329
        int nch = (Hout + C9CHUNK - 1) / C9CHUNK;
        conv9_lds<1><<<dim3(nch, 8), 512, 0, stream>>>(
            b1, cur, w18, b18, Hin, Hout, 8, 4, 2.f);
        scan_fill<<<dim3(4, 8), 1024, 0, stream>>>(cur, b1, a2, 26214, 2, ACT_ELU,
                                                   1, 0, preG, (uint4*)nxt);
        { u32* t = cur; cur = nxt; nxt = t; }
        Hin = 26214;
    }

    // ---- layer 19: conv(358, 2->5ch) folded widths 4->2 -> kmax 800 -> ELU ----
    {
        int Hout = Hin + 714 - 358 + 1;   // 26571
        conv_hist_t<2,5><<<dim3((Hout + 255)/256, 2), 256, 0, stream>>>(
            b1, cur, w19, b19, Hin, Hout, 358, 357, 4, 2, 1, 2.f);
        scan_fill<<<dim3(1, 10), 1024, 0, stream>>>(cur, b1, a2, 800, 5, ACT_ELU,
                                                    1, 0, preG, (uint4*)nxt);
    }

    // ---- FC + log_softmax ----
    fc_dot<<<1000, 256, 0, stream>>>(b1, Wfc, bfc, logits);
    lsm<<<1, 1024, 0, stream>>>(logits, (float*)d_out);
}

// Round 25
// 726.318 us; speedup vs baseline: 3.7724x; 3.7724x over previous
//
#include <hip/hip_runtime.h>
#include <math.h>

typedef unsigned int u32;
typedef unsigned long long u64;

#define STRIDE 262656          // per-column stride in floats
#define KSHIFT 15
#define KROUND 0x4000u
#define BAND   6144            // 24 exponents x 256 mantissa steps per sign
#define NB     12288           // bins per column
#define PA17   0x7100u
#define NA17   0x17700u
#define NCOLS  16
#define ZW     (NB*NCOLS)      // u32 words in one bin buffer
#define ACT_PRELU 0
#define ACT_RELU  1
#define ACT_ELU   2

__device__ __forceinline__ float k2f(u32 k){
    u32 u = (k & 0x80000000u) ? k : (k ^ 0x7FFFFFFFu);
    return __uint_as_float(u);
}
__device__ __forceinline__ int bin_of(float v){
    float av = fabsf(v);
    av = fminf(fmaxf(av, 0.00390625f), 65535.96875f);
    u32 u = __float_as_uint(av);
    if (v < 0.f){
        u32 k = 0x80000000u | u;
        int b = (int)(((k + KROUND) >> KSHIFT) - NA17);
        b = b < 0 ? 0 : (b > BAND-1 ? BAND-1 : b);
        return BAND + b;
    } else {
        u32 k = u ^ 0x7FFFFFFFu;
        int b = (int)(((k + KROUND) >> KSHIFT) - PA17);
        b = b < 0 ? 0 : (b > BAND-1 ? BAND-1 : b);
        return b;
    }
}
__device__ __forceinline__ float bin_val(int bin){
    u32 k17 = (bin < BAND) ? ((u32)bin + PA17) : ((u32)(bin - BAND) + NA17);
    return k2f(k17 << KSHIFT);
}

// wave run-length dedup -> one GLOBAL atomic per run per wave
__device__ __forceinline__ void hist_add(u32* __restrict__ Hc, int bin, bool valid, int lane){
    u32 bn = valid ? (u32)bin : 0xFFFFFFFFu;
    u32 prev = __shfl_up(bn, 1);
    bool diff = (lane == 0) || (prev != bn);
    u64 m = __ballot(diff || !valid);
    if (valid && diff){
        u64 above = m & ~((2ull << lane) - 1ull);
        int nxt = above ? (__ffsll((unsigned long long)above) - 1) : 64;
        atomicAdd(&Hc[bin], (u32)(nxt - lane));
    }
}

// wave run-length dedup -> one packed-u16 LDS atomic per run per wave
__device__ __forceinline__ void lds_hist_dedup(u32* __restrict__ hist, int bin, bool valid, int lane){
    u32 bn = valid ? (u32)bin : 0xFFFFFFFFu;
    u32 prev = __shfl_up(bn, 1);
    bool diff = (lane == 0) || (prev != bn);
    u64 m = __ballot(diff || !valid);
    if (valid && diff){
        u64 above = m & ~((2ull << lane) - 1ull);
        int nxt = above ? (__ffsll((unsigned long long)above) - 1) : 64;
        u32 cnt = (u32)(nxt - lane);
        atomicAdd(&hist[bin >> 1], cnt << ((bin & 1) * 16));
    }
}

// ---------------- fold+transpose x -> fx[8][STRIDE]; also zero bin0 ----------------
__global__ __launch_bounds__(256) void foldx(const float* __restrict__ x, float* __restrict__ fx,
                                             uint4* __restrict__ zb)
{
    __shared__ float4 tile[1024];    // 256 rows x 16 floats
    const int tid = threadIdx.x;
    const int h0 = blockIdx.x * 256;
    for (int i = tid; i < 1024; i += 256) tile[i] = ((const float4*)x)[(size_t)h0*4 + i];
    __syncthreads();
    float4 a = tile[tid*4+0], b = tile[tid*4+1], c = tile[tid*4+2], d = tile[tid*4+3];
    const int h = h0 + tid;
    fx[(size_t)0*STRIDE + h] = a.x + a.y;
    fx[(size_t)1*STRIDE + h] = a.z + a.w;
    fx[(size_t)2*STRIDE + h] = b.x + b.y;
    fx[(size_t)3*STRIDE + h] = b.z + b.w;
    fx[(size_t)4*STRIDE + h] = c.x + c.y;
    fx[(size_t)5*STRIDE + h] = c.z + c.w;
    fx[(size_t)6*STRIDE + h] = d.x + d.y;
    fx[(size_t)7*STRIDE + h] = d.z + d.w;
    const uint4 z = make_uint4(0,0,0,0);
    for (int i = blockIdx.x*256 + tid; i < ZW/4; i += gridDim.x*256) zb[i] = z;
}

// ---------------- layer-0 conv+hist: float4 shifted window, 4 outputs/thread ----------------
#define C0CHUNK 8192             // 4 tiles of 2048; 33 chunks x 16 cols = 528 blocks (~2/CU)
__global__ __launch_bounds__(512) void conv0_lds(const float* __restrict__ fx, u32* __restrict__ H,
                                                 const float* __restrict__ w0, const float* __restrict__ b0)
{
    __shared__ u32 hist[NB/2];                 // 24 KB packed u16 pairs
    __shared__ __align__(16) float s0f[2148];  // window floats [t0-98, t0+2049]; 537 float4s
    __shared__ float sw[100];                  // sw[99] = 0 pad
    const int colv = blockIdx.y;               // 0..15 = o*8 + wp
    const int o = colv >> 3, wp = colv & 7;
    const int tid = threadIdx.x;
    const int p0 = blockIdx.x * C0CHUNK;
    const int p1 = min(p0 + C0CHUNK, 262242);
    if (p0 >= 262242) return;
    for (int i = tid; i < NB/2; i += 512) hist[i] = 0;
    if (tid < 99) sw[tid] = w0[o*99 + tid];
    if (tid == 99) sw[99] = 0.f;
    const float bias = 2.f * b0[o];            // fold doubles bias
    __syncthreads();
    const float* fc = fx + (size_t)wp * STRIDE;
    const float4* s4 = (const float4*)s0f;
    for (int t0 = p0; t0 < p1; t0 += 2048){
        for (int i = tid; i < 2148; i += 512){
            int h = t0 - 98 + i;
            s0f[i] = (h >= 0 && h < 262144) ? fc[h] : 0.f;
        }
        __syncthreads();
        float a0 = bias, a1 = bias, a2 = bias, a3 = bias;
        float4 c = s4[tid];
        #pragma unroll
        for (int jb = 0; jb < 25; jb++){
            float4 n = s4[tid + jb + 1];
            float w0_ = sw[4*jb+0], w1_ = sw[4*jb+1], w2_ = sw[4*jb+2], w3_ = sw[4*jb+3];
            a0 += w0_*c.x; a1 += w0_*c.y; a2 += w0_*c.z; a3 += w0_*c.w;
            a0 += w1_*c.y; a1 += w1_*c.z; a2 += w1_*c.w; a3 += w1_*n.x;
            a0 += w2_*c.z; a1 += w2_*c.w; a2 += w2_*n.x; a3 += w2_*n.y;
            a0 += w3_*c.w; a1 += w3_*n.x; a2 += w3_*n.y; a3 += w3_*n.z;   // sw[99]=0
            c = n;
        }
        int hp = t0 + tid*4;
        if (hp     < p1){ int b = bin_of(a0); atomicAdd(&hist[b>>1], 1u << ((b&1)*16)); }
        if (hp + 1 < p1){ int b = bin_of(a1); atomicAdd(&hist[b>>1], 1u << ((b&1)*16)); }
        if (hp + 2 < p1){ int b = bin_of(a2); atomicAdd(&hist[b>>1], 1u << ((b&1)*16)); }
        if (hp + 3 < p1){ int b = bin_of(a3); atomicAdd(&hist[b>>1], 1u << ((b&1)*16)); }
        __syncthreads();
    }
    u32* Hc = H + (size_t)colv * NB;
    for (int i = tid; i < NB/2; i += 512){
        u32 w = hist[i];
        if (w){
            u32 lo = w & 0xFFFFu, hi = w >> 16;
            if (lo) atomicAdd(&Hc[2*i],   lo);
            if (hi) atomicAdd(&Hc[2*i+1], hi);
        }
    }
}

// ---------------- K=9 conv+hist: float4 shifted window, 4 outputs/thread ----------------
#define C9CHUNK 8192             // 4 tiles of 2048 per block
template<int FOLDIN>
__global__ __launch_bounds__(512) void conv9_lds(
    const float* __restrict__ In, u32* __restrict__ H,
    const float* __restrict__ Wt, const float* __restrict__ Bs,
    int Hin, int Hout, int Wi, int Wo, float bscale)
{
    __shared__ u32 hist[NB/2];                 // 24 KB
    __shared__ __align__(16) float s0f[2056];  // window: logical float i = h - (t0-8), i in [0,2056)
    __shared__ __align__(16) float s1f[2056];
    const int colv = blockIdx.y;               // o*Wo + wp
    const int o = colv / Wo, wp = colv % Wo;
    const int tid = threadIdx.x;
    const int lane = tid & 63;
    const int p0 = blockIdx.x * C9CHUNK;
    const int p1 = min(p0 + C9CHUNK, Hout);
    if (p0 >= Hout) return;
    for (int i = tid; i < NB/2; i += 512) hist[i] = 0;
    float w0r[9], w1r[9];
    #pragma unroll
    for (int j = 0; j < 9; j++){ w0r[j] = Wt[(o*2)*9 + j]; w1r[j] = Wt[(o*2)*9 + 9 + j]; }
    const float bv = bscale * Bs[o];
    __syncthreads();
    const float* i00 = In + (size_t)(0*Wi + (FOLDIN ? 2*wp   : wp))*STRIDE;
    const float* i01 = In + (size_t)(0*Wi + (FOLDIN ? 2*wp+1 : wp))*STRIDE;
    const float* i10 = In + (size_t)(1*Wi + (FOLDIN ? 2*wp   : wp))*STRIDE;
    const float* i11 = In + (size_t)(1*Wi + (FOLDIN ? 2*wp+1 : wp))*STRIDE;
    const float4* s40 = (const float4*)s0f;
    const float4* s41 = (const float4*)s1f;
    for (int t0 = p0; t0 < p1; t0 += 2048){
        for (int i = tid; i < 2056; i += 512){
            int h = t0 - 8 + i;
            float v0 = 0.f, v1 = 0.f;
            if (h >= 0 && h < Hin){
                v0 = FOLDIN ? (i00[h] + i01[h]) : i00[h];
                v1 = FOLDIN ? (i10[h] + i11[h]) : i10[h];
            }
            s0f[i] = v0; s1f[i] = v1;
        }
        __syncthreads();
        // outputs hp = t0 + 4*tid + r (r=0..3); tap j reads logical float 4*tid + r + j
        float a0 = bv, a1 = bv, a2 = bv, a3 = bv;
        {   // channel 0 taps j=0..8 ascending (preserve original accumulation order)
            float4 X = s40[tid], Y = s40[tid+1], Z = s40[tid+2];
            a0 += w0r[0]*X.x; a1 += w0r[0]*X.y; a2 += w0r[0]*X.z; a3 += w0r[0]*X.w;
            a0 += w0r[1]*X.y; a1 += w0r[1]*X.z; a2 += w0r[1]*X.w; a3 += w0r[1]*Y.x;
            a0 += w0r[2]*X.z; a1 += w0r[2]*X.w; a2 += w0r[2]*Y.x; a3 += w0r[2]*Y.y;
            a0 += w0r[3]*X.w; a1 += w0r[3]*Y.x; a2 += w0r[3]*Y.y; a3 += w0r[3]*Y.z;
            a0 += w0r[4]*Y.x; a1 += w0r[4]*Y.y; a2 += w0r[4]*Y.z; a3 += w0r[4]*Y.w;
            a0 += w0r[5]*Y.y; a1 += w0r[5]*Y.z; a2 += w0r[5]*Y.w; a3 += w0r[5]*Z.x;
            a0 += w0r[6]*Y.z; a1 += w0r[6]*Y.w; a2 += w0r[6]*Z.x; a3 += w0r[6]*Z.y;
            a0 += w0r[7]*Y.w; a1 += w0r[7]*Z.x; a2 += w0r[7]*Z.y; a3 += w0r[7]*Z.z;
            a0 += w0r[8]*Z.x; a1 += w0r[8]*Z.y; a2 += w0r[8]*Z.z; a3 += w0r[8]*Z.w;
        }
        {   // then channel 1
            float4 X = s41[tid], Y = s41[tid+1], Z = s41[tid+2];
            a0 += w1r[0]*X.x; a1 += w1r[0]*X.y; a2 += w1r[0]*X.z; a3 += w1r[0]*X.w;
            a0 += w1r[1]*X.y; a1 += w1r[1]*X.z; a2 += w1r[1]*X.w; a3 += w1r[1]*Y.x;
            a0 += w1r[2]*X.z; a1 += w1r[2]*X.w; a2 += w1r[2]*Y.x; a3 += w1r[2]*Y.y;
            a0 += w1r[3]*X.w; a1 += w1r[3]*Y.x; a2 += w1r[3]*Y.y; a3 += w1r[3]*Y.z;
            a0 += w1r[4]*Y.x; a1 += w1r[4]*Y.y; a2 += w1r[4]*Y.z; a3 += w1r[4]*Y.w;
            a0 += w1r[5]*Y.y; a1 += w1r[5]*Y.z; a2 += w1r[5]*Y.w; a3 += w1r[5]*Z.x;
            a0 += w1r[6]*Y.z; a1 += w1r[6]*Y.w; a2 += w1r[6]*Z.x; a3 += w1r[6]*Z.y;
            a0 += w1r[7]*Y.w; a1 += w1r[7]*Z.x; a2 += w1r[7]*Z.y; a3 += w1r[7]*Z.z;
            a0 += w1r[8]*Z.x; a1 += w1r[8]*Z.y; a2 += w1r[8]*Z.z; a3 += w1r[8]*Z.w;
        }
        int hp = t0 + tid*4;
        lds_hist_dedup(hist, bin_of(a0), hp     < p1, lane);
        lds_hist_dedup(hist, bin_of(a1), hp + 1 < p1, lane);
        lds_hist_dedup(hist, bin_of(a2), hp + 2 < p1, lane);
        lds_hist_dedup(hist, bin_of(a3), hp + 3 < p1, lane);
        __syncthreads();
    }
    u32* Hc = H + (size_t)colv * NB;
    for (int i = tid; i < NB/2; i += 512){
        u32 w = hist[i];
        if (w){
            u32 lo = w & 0xFFFFu, hi = w >> 16;
            if (lo) atomicAdd(&Hc[2*i],   lo);
            if (hi) atomicAdd(&Hc[2*i+1], hi);
        }
    }
}

// ---------------- layer-19 conv+hist (K=358, 2->5ch; global dedup atomics) ----------------
template<int INC, int OUTC>
__global__ __launch_bounds__(256) void conv_hist_t(
    const float* __restrict__ In, u32* __restrict__ H,
    const float* __restrict__ Wt, const float* __restrict__ Bs,
    int Hin, int Hout, int K, int pad, int Wi, int Wo, int foldIn, float bscale)
{
    __shared__ float sIn[INC][613];
    __shared__ float sW[OUTC*INC*358];
    const int wp = blockIdx.y;
    const int h0 = blockIdx.x * 256;
    const int tid = threadIdx.x;
    const int lane = tid & 63;
    const int tl = 256 + K - 1;
    for (int t = tid; t < INC*tl; t += 256){
        int c = t / tl, r = t - c*tl;
        int h = h0 - pad + r;
        float v = 0.f;
        if (h >= 0 && h < Hin){
            if (foldIn) v = In[(size_t)(c*Wi + 2*wp)*STRIDE + h] + In[(size_t)(c*Wi + 2*wp + 1)*STRIDE + h];
            else        v = In[(size_t)(c*Wi + wp)*STRIDE + h];
        }
        sIn[c][r] = v;
    }
    for (int t = tid; t < OUTC*INC*K; t += 256) sW[t] = Wt[t];
    __syncthreads();
    int hp = h0 + tid;
    bool valid = (hp < Hout);
    float acc[OUTC];
    #pragma unroll
    for (int o = 0; o < OUTC; o++) acc[o] = bscale * Bs[o];
    for (int c = 0; c < INC; c++){
        for (int j = 0; j < K; j++){
            float xv = sIn[c][tid + j];
            #pragma unroll
            for (int o = 0; o < OUTC; o++) acc[o] += sW[(o*INC + c)*K + j] * xv;
        }
    }
    #pragma unroll
    for (int o = 0; o < OUTC; o++)
        hist_add(H + (size_t)(o*Wo + wp)*NB, bin_of(acc[o]), valid, lane);
}

// ---------------- fused scan + reconstruct (binary search PER RUN) + next-bin zeroing ----------------
__global__ __launch_bounds__(1024) void scan_fill(
    const u32* __restrict__ H, float* __restrict__ dst, const float* __restrict__ alphaPtr,
    int kOut, int dup, int act, uint4* __restrict__ zb)
{
    __shared__ u32 pre[NB];          // 48 KB inclusive prefix
    __shared__ u32 warr[16];
    const int col = blockIdx.y;
    const int tid = threadIdx.x;
    const int lane = tid & 63, wv = tid >> 6;
    const u32* Hc = H + (size_t)col * NB;
    for (int i = tid; i < NB; i += 1024) pre[i] = Hc[i];
    __syncthreads();
    const int base = tid * 12;
    u32 v[12]; u32 s = 0;
    #pragma unroll
    for (int i = 0; i < 12; i++){ v[i] = pre[base + i]; s += v[i]; v[i] = s; }
    u32 ss = s;
    #pragma unroll
    for (int d = 1; d < 64; d <<= 1){
        u32 t = __shfl_up(ss, d);
        if (lane >= d) ss += t;
    }
    if (lane == 63) warr[wv] = ss;
    __syncthreads();
    u32 wb = 0;
    #pragma unroll
    for (int w = 0; w < 16; w++) wb += (w < wv) ? warr[w] : 0u;
    u32 excl = wb + ss - s;
    #pragma unroll
    for (int i = 0; i < 12; i++) pre[base + i] = v[i] + excl;
    __syncthreads();

    const int S  = gridDim.x;
    const int nr = kOut / dup;
    const int per = (nr + S*1024 - 1) / (S*1024);
    int i = (blockIdx.x*1024 + tid) * per;
    const int i1 = min(i + per, nr);
    float* d = dst + (size_t)col * STRIDE;
    const float alpha = alphaPtr[0];
    int lo0 = 0;                                  // monotone lower bound across runs
    while (i < i1){
        int lo = lo0, hi = NB - 1;                // smallest bin with pre[bin] > i
        while (lo < hi){ int m = (lo + hi) >> 1; if (pre[m] > (u32)i) hi = m; else lo = m + 1; }
        float vv = bin_val(lo);
        if (act == ACT_PRELU)      vv = (vv >= 0.f) ? vv : alpha * vv;
        else if (act == ACT_RELU)  vv = (vv > 0.f) ? vv : 0.f;
        else                       vv = (vv > 0.f) ? vv : expm1f(vv);
        int e = (int)min((u32)i1, pre[lo]);
        for (; i < e; i++){
            int bse = i * dup;
            for (int dd = 0; dd < dup; dd++) d[bse + dd] = vv;
        }
        lo0 = lo + 1;                             // next rank's bin is strictly above lo
    }
    // zero the other bin buffer for the next layer (vectorized)
    const uint4 z = make_uint4(0,0,0,0);
    int lin = (blockIdx.y * gridDim.x + blockIdx.x) * 1024 + tid;
    int tot = gridDim.x * gridDim.y * 1024;
    for (int q = lin; q < ZW/4; q += tot) zb[q] = z;
}

// ---------------- FC: 1000 logits, one block each; then log_softmax ----------------
__global__ __launch_bounds__(256) void fc_dot(const float* __restrict__ A, const float* __restrict__ Wfc,
                                              const float* __restrict__ bfc, float* __restrict__ logits)
{
    const int t = blockIdx.x;            // 0..999
    const int o = t / 200, j = t - o*200;
    const float* wrow = Wfc + (size_t)j*1600;
    float acc = 0.f;
    for (int q = threadIdx.x; q < 1600; q += 256){
        int p = q >> 1, wq = q & 1;
        acc += wrow[q] * A[(size_t)(o*2 + wq)*STRIDE + p];
    }
    __shared__ float red[256];
    red[threadIdx.x] = acc;
    __syncthreads();
    for (int s = 128; s > 0; s >>= 1){
        if (threadIdx.x < s) red[threadIdx.x] += red[threadIdx.x + s];
        __syncthreads();
    }
    if (threadIdx.x == 0) logits[t] = red[0] + bfc[j];
}

__global__ __launch_bounds__(1024) void lsm(const float* __restrict__ logits, float* __restrict__ out)
{
    const int tid = threadIdx.x;
    __shared__ float red[1024];
    float lg = (tid < 1000) ? logits[tid] : -INFINITY;
    red[tid] = lg;
    __syncthreads();
    for (int s = 512; s > 0; s >>= 1){
        if (tid < s) red[tid] = fmaxf(red[tid], red[tid + s]);
        __syncthreads();
    }
    float m = red[0];
    __syncthreads();
    red[tid] = (tid < 1000) ? expf(lg - m) : 0.f;
    __syncthreads();
    for (int s = 512; s > 0; s >>= 1){
        if (tid < s) red[tid] += red[tid + s];
        __syncthreads();
    }
    float lse = logf(red[0]);
    if (tid < 1000) out[tid] = lg - m - lse;
}

extern "C" void kernel_launch(void* const* d_in, const int* in_sizes, int n_in,
                              void* d_out, int out_size, void* d_ws, size_t ws_size,
                              hipStream_t stream)
{
    (void)in_sizes; (void)n_in; (void)out_size;
    const size_t need = (size_t)24*STRIDE*4 + (size_t)2*ZW*4 + 4096;
    if (ws_size < need) return;

    const float* x   = (const float*)d_in[0];
    const float* w0  = (const float*)d_in[1];
    const float* b0  = (const float*)d_in[2];
    const float* wm  = (const float*)d_in[3];
    const float* bm  = (const float*)d_in[4];
    const float* w18 = (const float*)d_in[5];
    const float* b18 = (const float*)d_in[6];
    const float* w19 = (const float*)d_in[7];
    const float* b19 = (const float*)d_in[8];
    const float* a1  = (const float*)d_in[9];
    const float* a2  = (const float*)d_in[10];
    const float* Wfc = (const float*)d_in[11];
    const float* bfc = (const float*)d_in[12];

    float* b1   = (float*)d_ws;
    float* fx   = b1 + (size_t)16*STRIDE;
    u32*  bin0  = (u32*)(fx + (size_t)8*STRIDE);
    u32*  bin1  = bin0 + (size_t)ZW;
    float* logits = (float*)(bin1 + (size_t)ZW);

    u32* cur = bin0;
    u32* nxt = bin1;

    // fold+transpose x; zero bin0
    foldx<<<1024, 256, 0, stream>>>(x, fx, (uint4*)cur);

    // ---- layer 0: conv(99, pad 98) -> fold(x2 dup) -> kmax 262144 -> PReLU(a1) ----
    conv0_lds<<<dim3(33, 16), 512, 0, stream>>>(fx, cur, w0, b0);
    scan_fill<<<dim3(16, 16), 1024, 0, stream>>>(cur, b1, a1, 262144, 2, ACT_PRELU, (uint4*)nxt);
    { u32* t = cur; cur = nxt; nxt = t; }
    int Hin = 262144;

    // ---- layers 1..17: conv(9, pad 8) -> kmax -> PReLU(a2)/ReLU ----
    static const int ks[17] = {249036,235929,222822,209715,196608,183500,170393,157286,
                               144179,131072,117964,104857,91750,78643,65536,52428,39321};
    for (int i = 0; i < 17; i++){
        int Hout = Hin + 8;
        int nch = (Hout + C9CHUNK - 1) / C9CHUNK;
        conv9_lds<0><<<dim3(nch, 16), 512, 0, stream>>>(
            b1, cur, wm + (size_t)i*36, bm + (size_t)i*2, Hin, Hout, 8, 8, 1.f);
        scan_fill<<<dim3(16, 16), 1024, 0, stream>>>(cur, b1, a2, ks[i], 1,
                                                     (i == 0) ? ACT_PRELU : ACT_RELU, (uint4*)nxt);
        { u32* t = cur; cur = nxt; nxt = t; }
        Hin = ks[i];
    }

    // ---- layer 18: conv(9) -> fold(widths 8->4, x2 dup) -> kmax 26214 -> ELU ----
    {
        int Hout = Hin + 8;   // 39329
        int nch = (Hout + C9CHUNK - 1) / C9CHUNK;
        conv9_lds<1><<<dim3(nch, 8), 512, 0, stream>>>(
            b1, cur, w18, b18, Hin, Hout, 8, 4, 2.f);
        scan_fill<<<dim3(4, 8), 1024, 0, stream>>>(cur, b1, a2, 26214, 2, ACT_ELU, (uint4*)nxt);
        { u32* t = cur; cur = nxt; nxt = t; }
        Hin = 26214;
    }

    // ---- layer 19: conv(358, pad 357, 2->5ch) -> fold(widths 4->2, x5 dup) -> kmax 800 -> ELU ----
    {
        int Hout = Hin + 714 - 358 + 1;   // 26571
        conv_hist_t<2,5><<<dim3((Hout + 255)/256, 2), 256, 0, stream>>>(
            b1, cur, w19, b19, Hin, Hout, 358, 357, 4, 2, 1, 2.f);
        scan_fill<<<dim3(1, 10), 1024, 0, stream>>>(cur, b1, a2, 800, 5, ACT_ELU, (uint4*)nxt);
    }

    // ---- FC + log_softmax ----
    fc_dot<<<1000, 256, 0, stream>>>(b1, Wfc, bfc, logits);
    lsm<<<1, 1024, 0, stream>>>(logits, (float*)d_out);
}

// Round 26
// 667.533 us; speedup vs baseline: 4.1046x; 1.0881x over previous
//
#include <hip/hip_runtime.h>
#include <math.h>

typedef unsigned int u32;
typedef unsigned long long u64;

#define STRIDE 262656          // per-column stride in floats
#define KSHIFT 16
#define KROUND 0x8000u
#define BAND   3072            // 24 exponents x 128 mantissa steps per sign
#define NB     6144            // bins per column
#define PA16   0x3880u
#define NA16   0xBB80u
#define NCOLS  16
#define ZW     (NB*NCOLS)      // u32 words in one bin buffer
#define ACT_PRELU 0
#define ACT_RELU  1
#define ACT_ELU   2

__device__ __forceinline__ float k2f(u32 k){
    u32 u = (k & 0x80000000u) ? k : (k ^ 0x7FFFFFFFu);
    return __uint_as_float(u);
}
__device__ __forceinline__ int bin_of(float v){
    float av = fabsf(v);
    av = fminf(fmaxf(av, 0.00390625f), 65535.96875f);
    u32 u = __float_as_uint(av);
    if (v < 0.f){
        u32 k = 0x80000000u | u;
        int b = (int)(((k + KROUND) >> KSHIFT) - NA16);
        b = b < 0 ? 0 : (b > BAND-1 ? BAND-1 : b);
        return BAND + b;
    } else {
        u32 k = u ^ 0x7FFFFFFFu;
        int b = (int)(((k + KROUND) >> KSHIFT) - PA16);
        b = b < 0 ? 0 : (b > BAND-1 ? BAND-1 : b);
        return b;
    }
}
__device__ __forceinline__ float bin_val(int bin){
    u32 k16 = (bin < BAND) ? ((u32)bin + PA16) : ((u32)(bin - BAND) + NA16);
    return k2f(k16 << KSHIFT);
}

// wave run-length dedup -> one GLOBAL atomic per run per wave
__device__ __forceinline__ void hist_add(u32* __restrict__ Hc, int bin, bool valid, int lane){
    u32 bn = valid ? (u32)bin : 0xFFFFFFFFu;
    u32 prev = __shfl_up(bn, 1);
    bool diff = (lane == 0) || (prev != bn);
    u64 m = __ballot(diff || !valid);
    if (valid && diff){
        u64 above = m & ~((2ull << lane) - 1ull);
        int nxt = above ? (__ffsll((unsigned long long)above) - 1) : 64;
        atomicAdd(&Hc[bin], (u32)(nxt - lane));
    }
}

// wave run-length dedup -> one packed-u16 LDS atomic per run per wave
__device__ __forceinline__ void lds_hist_dedup(u32* __restrict__ hist, int bin, bool valid, int lane){
    u32 bn = valid ? (u32)bin : 0xFFFFFFFFu;
    u32 prev = __shfl_up(bn, 1);
    bool diff = (lane == 0) || (prev != bn);
    u64 m = __ballot(diff || !valid);
    if (valid && diff){
        u64 above = m & ~((2ull << lane) - 1ull);
        int nxt = above ? (__ffsll((unsigned long long)above) - 1) : 64;
        u32 cnt = (u32)(nxt - lane);
        atomicAdd(&hist[bin >> 1], cnt << ((bin & 1) * 16));
    }
}

// ---------------- fold+transpose x -> fx[8][STRIDE]; also zero bin0 ----------------
__global__ __launch_bounds__(256) void foldx(const float* __restrict__ x, float* __restrict__ fx,
                                             uint4* __restrict__ zb)
{
    __shared__ float4 tile[1024];    // 256 rows x 16 floats
    const int tid = threadIdx.x;
    const int h0 = blockIdx.x * 256;
    for (int i = tid; i < 1024; i += 256) tile[i] = ((const float4*)x)[(size_t)h0*4 + i];
    __syncthreads();
    float4 a = tile[tid*4+0], b = tile[tid*4+1], c = tile[tid*4+2], d = tile[tid*4+3];
    const int h = h0 + tid;
    fx[(size_t)0*STRIDE + h] = a.x + a.y;
    fx[(size_t)1*STRIDE + h] = a.z + a.w;
    fx[(size_t)2*STRIDE + h] = b.x + b.y;
    fx[(size_t)3*STRIDE + h] = b.z + b.w;
    fx[(size_t)4*STRIDE + h] = c.x + c.y;
    fx[(size_t)5*STRIDE + h] = c.z + c.w;
    fx[(size_t)6*STRIDE + h] = d.x + d.y;
    fx[(size_t)7*STRIDE + h] = d.z + d.w;
    const uint4 z = make_uint4(0,0,0,0);
    for (int i = blockIdx.x*256 + tid; i < ZW/4; i += gridDim.x*256) zb[i] = z;
}

// ---------------- layer-0 conv+hist: float4 shifted window, 4 outputs/thread ----------------
#define C0CHUNK 8192             // 4 tiles of 2048; 33 chunks x 16 cols = 528 blocks (~2/CU)
__global__ __launch_bounds__(512) void conv0_lds(const float* __restrict__ fx, u32* __restrict__ H,
                                                 const float* __restrict__ w0, const float* __restrict__ b0)
{
    __shared__ u32 hist[NB/2];                 // 12 KB packed u16 pairs
    __shared__ __align__(16) float s0f[2148];  // window floats [t0-98, t0+2049]; 537 float4s
    __shared__ float sw[100];                  // sw[99] = 0 pad
    const int colv = blockIdx.y;               // 0..15 = o*8 + wp
    const int o = colv >> 3, wp = colv & 7;
    const int tid = threadIdx.x;
    const int p0 = blockIdx.x * C0CHUNK;
    const int p1 = min(p0 + C0CHUNK, 262242);
    if (p0 >= 262242) return;
    for (int i = tid; i < NB/2; i += 512) hist[i] = 0;
    if (tid < 99) sw[tid] = w0[o*99 + tid];
    if (tid == 99) sw[99] = 0.f;
    const float bias = 2.f * b0[o];            // fold doubles bias
    __syncthreads();
    const float* fc = fx + (size_t)wp * STRIDE;
    const float4* s4 = (const float4*)s0f;
    for (int t0 = p0; t0 < p1; t0 += 2048){
        for (int i = tid; i < 2148; i += 512){
            int h = t0 - 98 + i;
            s0f[i] = (h >= 0 && h < 262144) ? fc[h] : 0.f;
        }
        __syncthreads();
        float a0 = bias, a1 = bias, a2 = bias, a3 = bias;
        float4 c = s4[tid];
        #pragma unroll
        for (int jb = 0; jb < 25; jb++){
            float4 n = s4[tid + jb + 1];
            float w0_ = sw[4*jb+0], w1_ = sw[4*jb+1], w2_ = sw[4*jb+2], w3_ = sw[4*jb+3];
            a0 += w0_*c.x; a1 += w0_*c.y; a2 += w0_*c.z; a3 += w0_*c.w;
            a0 += w1_*c.y; a1 += w1_*c.z; a2 += w1_*c.w; a3 += w1_*n.x;
            a0 += w2_*c.z; a1 += w2_*c.w; a2 += w2_*n.x; a3 += w2_*n.y;
            a0 += w3_*c.w; a1 += w3_*n.x; a2 += w3_*n.y; a3 += w3_*n.z;   // sw[99]=0
            c = n;
        }
        int hp = t0 + tid*4;
        if (hp     < p1){ int b = bin_of(a0); atomicAdd(&hist[b>>1], 1u << ((b&1)*16)); }
        if (hp + 1 < p1){ int b = bin_of(a1); atomicAdd(&hist[b>>1], 1u << ((b&1)*16)); }
        if (hp + 2 < p1){ int b = bin_of(a2); atomicAdd(&hist[b>>1], 1u << ((b&1)*16)); }
        if (hp + 3 < p1){ int b = bin_of(a3); atomicAdd(&hist[b>>1], 1u << ((b&1)*16)); }
        __syncthreads();
    }
    u32* Hc = H + (size_t)colv * NB;
    for (int i = tid; i < NB/2; i += 512){
        u32 w = hist[i];
        if (w){
            u32 lo = w & 0xFFFFu, hi = w >> 16;
            if (lo) atomicAdd(&Hc[2*i],   lo);
            if (hi) atomicAdd(&Hc[2*i+1], hi);
        }
    }
}

// ---------------- K=9 conv+hist: float4 shifted window, 4 outputs/thread ----------------
#define C9CHUNK 8192             // 4 tiles of 2048 per block
template<int FOLDIN>
__global__ __launch_bounds__(512) void conv9_lds(
    const float* __restrict__ In, u32* __restrict__ H,
    const float* __restrict__ Wt, const float* __restrict__ Bs,
    int Hin, int Hout, int Wi, int Wo, float bscale)
{
    __shared__ u32 hist[NB/2];                 // 12 KB
    __shared__ __align__(16) float s0f[2056];  // window: logical float i = h - (t0-8), i in [0,2056)
    __shared__ __align__(16) float s1f[2056];
    const int colv = blockIdx.y;               // o*Wo + wp
    const int o = colv / Wo, wp = colv % Wo;
    const int tid = threadIdx.x;
    const int lane = tid & 63;
    const int p0 = blockIdx.x * C9CHUNK;
    const int p1 = min(p0 + C9CHUNK, Hout);
    if (p0 >= Hout) return;
    for (int i = tid; i < NB/2; i += 512) hist[i] = 0;
    float w0r[9], w1r[9];
    #pragma unroll
    for (int j = 0; j < 9; j++){ w0r[j] = Wt[(o*2)*9 + j]; w1r[j] = Wt[(o*2)*9 + 9 + j]; }
    const float bv = bscale * Bs[o];
    __syncthreads();
    const float* i00 = In + (size_t)(0*Wi + (FOLDIN ? 2*wp   : wp))*STRIDE;
    const float* i01 = In + (size_t)(0*Wi + (FOLDIN ? 2*wp+1 : wp))*STRIDE;
    const float* i10 = In + (size_t)(1*Wi + (FOLDIN ? 2*wp   : wp))*STRIDE;
    const float* i11 = In + (size_t)(1*Wi + (FOLDIN ? 2*wp+1 : wp))*STRIDE;
    const float4* s40 = (const float4*)s0f;
    const float4* s41 = (const float4*)s1f;
    for (int t0 = p0; t0 < p1; t0 += 2048){
        for (int i = tid; i < 2056; i += 512){
            int h = t0 - 8 + i;
            float v0 = 0.f, v1 = 0.f;
            if (h >= 0 && h < Hin){
                v0 = FOLDIN ? (i00[h] + i01[h]) : i00[h];
                v1 = FOLDIN ? (i10[h] + i11[h]) : i10[h];
            }
            s0f[i] = v0; s1f[i] = v1;
        }
        __syncthreads();
        // outputs hp = t0 + 4*tid + r (r=0..3); tap j reads logical float 4*tid + r + j
        float a0 = bv, a1 = bv, a2 = bv, a3 = bv;
        {   // channel 0 taps j=0..8 ascending (preserve original accumulation order)
            float4 X = s40[tid], Y = s40[tid+1], Z = s40[tid+2];
            a0 += w0r[0]*X.x; a1 += w0r[0]*X.y; a2 += w0r[0]*X.z; a3 += w0r[0]*X.w;
            a0 += w0r[1]*X.y; a1 += w0r[1]*X.z; a2 += w0r[1]*X.w; a3 += w0r[1]*Y.x;
            a0 += w0r[2]*X.z; a1 += w0r[2]*X.w; a2 += w0r[2]*Y.x; a3 += w0r[2]*Y.y;
            a0 += w0r[3]*X.w; a1 += w0r[3]*Y.x; a2 += w0r[3]*Y.y; a3 += w0r[3]*Y.z;
            a0 += w0r[4]*Y.x; a1 += w0r[4]*Y.y; a2 += w0r[4]*Y.z; a3 += w0r[4]*Y.w;
            a0 += w0r[5]*Y.y; a1 += w0r[5]*Y.z; a2 += w0r[5]*Y.w; a3 += w0r[5]*Z.x;
            a0 += w0r[6]*Y.z; a1 += w0r[6]*Y.w; a2 += w0r[6]*Z.x; a3 += w0r[6]*Z.y;
            a0 += w0r[7]*Y.w; a1 += w0r[7]*Z.x; a2 += w0r[7]*Z.y; a3 += w0r[7]*Z.z;
            a0 += w0r[8]*Z.x; a1 += w0r[8]*Z.y; a2 += w0r[8]*Z.z; a3 += w0r[8]*Z.w;
        }
        {   // then channel 1
            float4 X = s41[tid], Y = s41[tid+1], Z = s41[tid+2];
            a0 += w1r[0]*X.x; a1 += w1r[0]*X.y; a2 += w1r[0]*X.z; a3 += w1r[0]*X.w;
            a0 += w1r[1]*X.y; a1 += w1r[1]*X.z; a2 += w1r[1]*X.w; a3 += w1r[1]*Y.x;
            a0 += w1r[2]*X.z; a1 += w1r[2]*X.w; a2 += w1r[2]*Y.x; a3 += w1r[2]*Y.y;
            a0 += w1r[3]*X.w; a1 += w1r[3]*Y.x; a2 += w1r[3]*Y.y; a3 += w1r[3]*Y.z;
            a0 += w1r[4]*Y.x; a1 += w1r[4]*Y.y; a2 += w1r[4]*Y.z; a3 += w1r[4]*Y.w;
            a0 += w1r[5]*Y.y; a1 += w1r[5]*Y.z; a2 += w1r[5]*Y.w; a3 += w1r[5]*Z.x;
            a0 += w1r[6]*Y.z; a1 += w1r[6]*Y.w; a2 += w1r[6]*Z.x; a3 += w1r[6]*Z.y;
            a0 += w1r[7]*Y.w; a1 += w1r[7]*Z.x; a2 += w1r[7]*Z.y; a3 += w1r[7]*Z.z;
            a0 += w1r[8]*Z.x; a1 += w1r[8]*Z.y; a2 += w1r[8]*Z.z; a3 += w1r[8]*Z.w;
        }
        int hp = t0 + tid*4;
        lds_hist_dedup(hist, bin_of(a0), hp     < p1, lane);
        lds_hist_dedup(hist, bin_of(a1), hp + 1 < p1, lane);
        lds_hist_dedup(hist, bin_of(a2), hp + 2 < p1, lane);
        lds_hist_dedup(hist, bin_of(a3), hp + 3 < p1, lane);
        __syncthreads();
    }
    u32* Hc = H + (size_t)colv * NB;
    for (int i = tid; i < NB/2; i += 512){
        u32 w = hist[i];
        if (w){
            u32 lo = w & 0xFFFFu, hi = w >> 16;
            if (lo) atomicAdd(&Hc[2*i],   lo);
            if (hi) atomicAdd(&Hc[2*i+1], hi);
        }
    }
}

// ---------------- layer-19 conv+hist (K=358, 2->5ch; global dedup atomics) ----------------
template<int INC, int OUTC>
__global__ __launch_bounds__(256) void conv_hist_t(
    const float* __restrict__ In, u32* __restrict__ H,
    const float* __restrict__ Wt, const float* __restrict__ Bs,
    int Hin, int Hout, int K, int pad, int Wi, int Wo, int foldIn, float bscale)
{
    __shared__ float sIn[INC][613];
    __shared__ float sW[OUTC*INC*358];
    const int wp = blockIdx.y;
    const int h0 = blockIdx.x * 256;
    const int tid = threadIdx.x;
    const int lane = tid & 63;
    const int tl = 256 + K - 1;
    for (int t = tid; t < INC*tl; t += 256){
        int c = t / tl, r = t - c*tl;
        int h = h0 - pad + r;
        float v = 0.f;
        if (h >= 0 && h < Hin){
            if (foldIn) v = In[(size_t)(c*Wi + 2*wp)*STRIDE + h] + In[(size_t)(c*Wi + 2*wp + 1)*STRIDE + h];
            else        v = In[(size_t)(c*Wi + wp)*STRIDE + h];
        }
        sIn[c][r] = v;
    }
    for (int t = tid; t < OUTC*INC*K; t += 256) sW[t] = Wt[t];
    __syncthreads();
    int hp = h0 + tid;
    bool valid = (hp < Hout);
    float acc[OUTC];
    #pragma unroll
    for (int o = 0; o < OUTC; o++) acc[o] = bscale * Bs[o];
    for (int c = 0; c < INC; c++){
        for (int j = 0; j < K; j++){
            float xv = sIn[c][tid + j];
            #pragma unroll
            for (int o = 0; o < OUTC; o++) acc[o] += sW[(o*INC + c)*K + j] * xv;
        }
    }
    #pragma unroll
    for (int o = 0; o < OUTC; o++)
        hist_add(H + (size_t)(o*Wo + wp)*NB, bin_of(acc[o]), valid, lane);
}

// ---------------- fused scan + reconstruct (binary search PER RUN) + next-bin zeroing ----------------
__global__ __launch_bounds__(1024) void scan_fill(
    const u32* __restrict__ H, float* __restrict__ dst, const float* __restrict__ alphaPtr,
    int kOut, int dup, int act, uint4* __restrict__ zb)
{
    __shared__ u32 pre[NB];          // 24 KB inclusive prefix
    __shared__ u32 warr[16];
    const int col = blockIdx.y;
    const int tid = threadIdx.x;
    const int lane = tid & 63, wv = tid >> 6;
    const u32* Hc = H + (size_t)col * NB;
    for (int i = tid; i < NB; i += 1024) pre[i] = Hc[i];
    __syncthreads();
    const int base = tid * 6;
    u32 v[6]; u32 s = 0;
    #pragma unroll
    for (int i = 0; i < 6; i++){ v[i] = pre[base + i]; s += v[i]; v[i] = s; }
    u32 ss = s;
    #pragma unroll
    for (int d = 1; d < 64; d <<= 1){
        u32 t = __shfl_up(ss, d);
        if (lane >= d) ss += t;
    }
    if (lane == 63) warr[wv] = ss;
    __syncthreads();
    u32 wb = 0;
    #pragma unroll
    for (int w = 0; w < 16; w++) wb += (w < wv) ? warr[w] : 0u;
    u32 excl = wb + ss - s;
    #pragma unroll
    for (int i = 0; i < 6; i++) pre[base + i] = v[i] + excl;
    __syncthreads();

    const int S  = gridDim.x;
    const int nr = kOut / dup;
    const int per = (nr + S*1024 - 1) / (S*1024);
    int i = (blockIdx.x*1024 + tid) * per;
    const int i1 = min(i + per, nr);
    float* d = dst + (size_t)col * STRIDE;
    const float alpha = alphaPtr[0];
    int lo0 = 0;                                  // monotone lower bound across runs
    while (i < i1){
        int lo = lo0, hi = NB - 1;                // smallest bin with pre[bin] > i
        while (lo < hi){ int m = (lo + hi) >> 1; if (pre[m] > (u32)i) hi = m; else lo = m + 1; }
        float vv = bin_val(lo);
        if (act == ACT_PRELU)      vv = (vv >= 0.f) ? vv : alpha * vv;
        else if (act == ACT_RELU)  vv = (vv > 0.f) ? vv : 0.f;
        else                       vv = (vv > 0.f) ? vv : expm1f(vv);
        int e = (int)min((u32)i1, pre[lo]);
        for (; i < e; i++){
            int bse = i * dup;
            for (int dd = 0; dd < dup; dd++) d[bse + dd] = vv;
        }
        lo0 = lo + 1;                             // next rank's bin is strictly above lo
    }
    // zero the other bin buffer for the next layer (vectorized)
    const uint4 z = make_uint4(0,0,0,0);
    int lin = (blockIdx.y * gridDim.x + blockIdx.x) * 1024 + tid;
    int tot = gridDim.x * gridDim.y * 1024;
    for (int q = lin; q < ZW/4; q += tot) zb[q] = z;
}

// ---------------- FC: 1000 logits, one block each; then log_softmax ----------------
__global__ __launch_bounds__(256) void fc_dot(const float* __restrict__ A, const float* __restrict__ Wfc,
                                              const float* __restrict__ bfc, float* __restrict__ logits)
{
    const int t = blockIdx.x;            // 0..999
    const int o = t / 200, j = t - o*200;
    const float* wrow = Wfc + (size_t)j*1600;
    float acc = 0.f;
    for (int q = threadIdx.x; q < 1600; q += 256){
        int p = q >> 1, wq = q & 1;
        acc += wrow[q] * A[(size_t)(o*2 + wq)*STRIDE + p];
    }
    __shared__ float red[256];
    red[threadIdx.x] = acc;
    __syncthreads();
    for (int s = 128; s > 0; s >>= 1){
        if (threadIdx.x < s) red[threadIdx.x] += red[threadIdx.x + s];
        __syncthreads();
    }
    if (threadIdx.x == 0) logits[t] = red[0] + bfc[j];
}

__global__ __launch_bounds__(1024) void lsm(const float* __restrict__ logits, float* __restrict__ out)
{
    const int tid = threadIdx.x;
    __shared__ float red[1024];
    float lg = (tid < 1000) ? logits[tid] : -INFINITY;
    red[tid] = lg;
    __syncthreads();
    for (int s = 512; s > 0; s >>= 1){
        if (tid < s) red[tid] = fmaxf(red[tid], red[tid + s]);
        __syncthreads();
    }
    float m = red[0];
    __syncthreads();
    red[tid] = (tid < 1000) ? expf(lg - m) : 0.f;
    __syncthreads();
    for (int s = 512; s > 0; s >>= 1){
        if (tid < s) red[tid] += red[tid + s];
        __syncthreads();
    }
    float lse = logf(red[0]);
    if (tid < 1000) out[tid] = lg - m - lse;
}

extern "C" void kernel_launch(void* const* d_in, const int* in_sizes, int n_in,
                              void* d_out, int out_size, void* d_ws, size_t ws_size,
                              hipStream_t stream)
{
    (void)in_sizes; (void)n_in; (void)out_size;
    const size_t need = (size_t)24*STRIDE*4 + (size_t)2*ZW*4 + 4096;
    if (ws_size < need) return;

    const float* x   = (const float*)d_in[0];
    const float* w0  = (const float*)d_in[1];
    const float* b0  = (const float*)d_in[2];
    const float* wm  = (const float*)d_in[3];
    const float* bm  = (const float*)d_in[4];
    const float* w18 = (const float*)d_in[5];
    const float* b18 = (const float*)d_in[6];
    const float* w19 = (const float*)d_in[7];
    const float* b19 = (const float*)d_in[8];
    const float* a1  = (const float*)d_in[9];
    const float* a2  = (const float*)d_in[10];
    const float* Wfc = (const float*)d_in[11];
    const float* bfc = (const float*)d_in[12];

    float* b1   = (float*)d_ws;
    float* fx   = b1 + (size_t)16*STRIDE;
    u32*  bin0  = (u32*)(fx + (size_t)8*STRIDE);
    u32*  bin1  = bin0 + (size_t)ZW;
    float* logits = (float*)(bin1 + (size_t)ZW);

    u32* cur = bin0;
    u32* nxt = bin1;

    // fold+transpose x; zero bin0
    foldx<<<1024, 256, 0, stream>>>(x, fx, (uint4*)cur);

    // ---- layer 0: conv(99, pad 98) -> fold(x2 dup) -> kmax 262144 -> PReLU(a1) ----
    conv0_lds<<<dim3(33, 16), 512, 0, stream>>>(fx, cur, w0, b0);
    scan_fill<<<dim3(16, 16), 1024, 0, stream>>>(cur, b1, a1, 262144, 2, ACT_PRELU, (uint4*)nxt);
    { u32* t = cur; cur = nxt; nxt = t; }
    int Hin = 262144;

    // ---- layers 1..17: conv(9, pad 8) -> kmax -> PReLU(a2)/ReLU ----
    static const int ks[17] = {249036,235929,222822,209715,196608,183500,170393,157286,
                               144179,131072,117964,104857,91750,78643,65536,52428,39321};
    for (int i = 0; i < 17; i++){
        int Hout = Hin + 8;
        int nch = (Hout + C9CHUNK - 1) / C9CHUNK;
        conv9_lds<0><<<dim3(nch, 16), 512, 0, stream>>>(
            b1, cur, wm + (size_t)i*36, bm + (size_t)i*2, Hin, Hout, 8, 8, 1.f);
        scan_fill<<<dim3(16, 16), 1024, 0, stream>>>(cur, b1, a2, ks[i], 1,
                                                     (i == 0) ? ACT_PRELU : ACT_RELU, (uint4*)nxt);
        { u32* t = cur; cur = nxt; nxt = t; }
        Hin = ks[i];
    }

    // ---- layer 18: conv(9) -> fold(widths 8->4, x2 dup) -> kmax 26214 -> ELU ----
    {
        int Hout = Hin + 8;   // 39329
        int nch = (Hout + C9CHUNK - 1) / C9CHUNK;
        conv9_lds<1><<<dim3(nch, 8), 512, 0, stream>>>(
            b1, cur, w18, b18, Hin, Hout, 8, 4, 2.f);
        scan_fill<<<dim3(4, 8), 1024, 0, stream>>>(cur, b1, a2, 26214, 2, ACT_ELU, (uint4*)nxt);
        { u32* t = cur; cur = nxt; nxt = t; }
        Hin = 26214;
    }

    // ---- layer 19: conv(358, pad 357, 2->5ch) -> fold(widths 4->2, x5 dup) -> kmax 800 -> ELU ----
    {
        int Hout = Hin + 714 - 358 + 1;   // 26571
        conv_hist_t<2,5><<<dim3((Hout + 255)/256, 2), 256, 0, stream>>>(
            b1, cur, w19, b19, Hin, Hout, 358, 357, 4, 2, 1, 2.f);
        scan_fill<<<dim3(1, 10), 1024, 0, stream>>>(cur, b1, a2, 800, 5, ACT_ELU, (uint4*)nxt);
    }

    // ---- FC + log_softmax ----
    fc_dot<<<1000, 256, 0, stream>>>(b1, Wfc, bfc, logits);
    lsm<<<1, 1024, 0, stream>>>(logits, (float*)d_out);
}

// Round 27
// 636.510 us; speedup vs baseline: 4.3046x; 1.0487x over previous
//
#include <hip/hip_runtime.h>
#include <math.h>

typedef unsigned int u32;
typedef unsigned long long u64;

#define STRIDE 262656          // per-column stride in floats
#define KSHIFT 17
#define KROUND 0x10000u
#define BAND   1536            // 24 exponents x 64 mantissa steps per sign
#define NB     3072            // bins per column
#define PA17B  0x1C40u
#define NA17B  0x5DC0u
#define NCOLS  16
#define ZW     (NB*NCOLS)      // u32 words in one bin buffer
#define ACT_PRELU 0
#define ACT_RELU  1
#define ACT_ELU   2

__device__ __forceinline__ float k2f(u32 k){
    u32 u = (k & 0x80000000u) ? k : (k ^ 0x7FFFFFFFu);
    return __uint_as_float(u);
}
__device__ __forceinline__ int bin_of(float v){
    float av = fabsf(v);
    av = fminf(fmaxf(av, 0.00390625f), 65535.96875f);
    u32 u = __float_as_uint(av);
    if (v < 0.f){
        u32 k = 0x80000000u | u;
        int b = (int)(((k + KROUND) >> KSHIFT) - NA17B);
        b = b < 0 ? 0 : (b > BAND-1 ? BAND-1 : b);
        return BAND + b;
    } else {
        u32 k = u ^ 0x7FFFFFFFu;
        int b = (int)(((k + KROUND) >> KSHIFT) - PA17B);
        b = b < 0 ? 0 : (b > BAND-1 ? BAND-1 : b);
        return b;
    }
}
__device__ __forceinline__ float bin_val(int bin){
    u32 k17 = (bin < BAND) ? ((u32)bin + PA17B) : ((u32)(bin - BAND) + NA17B);
    return k2f(k17 << KSHIFT);
}

// wave run-length dedup -> one GLOBAL atomic per run per wave
__device__ __forceinline__ void hist_add(u32* __restrict__ Hc, int bin, bool valid, int lane){
    u32 bn = valid ? (u32)bin : 0xFFFFFFFFu;
    u32 prev = __shfl_up(bn, 1);
    bool diff = (lane == 0) || (prev != bn);
    u64 m = __ballot(diff || !valid);
    if (valid && diff){
        u64 above = m & ~((2ull << lane) - 1ull);
        int nxt = above ? (__ffsll((unsigned long long)above) - 1) : 64;
        atomicAdd(&Hc[bin], (u32)(nxt - lane));
    }
}

// wave run-length dedup -> one packed-u16 LDS atomic per run per wave
__device__ __forceinline__ void lds_hist_dedup(u32* __restrict__ hist, int bin, bool valid, int lane){
    u32 bn = valid ? (u32)bin : 0xFFFFFFFFu;
    u32 prev = __shfl_up(bn, 1);
    bool diff = (lane == 0) || (prev != bn);
    u64 m = __ballot(diff || !valid);
    if (valid && diff){
        u64 above = m & ~((2ull << lane) - 1ull);
        int nxt = above ? (__ffsll((unsigned long long)above) - 1) : 64;
        u32 cnt = (u32)(nxt - lane);
        atomicAdd(&hist[bin >> 1], cnt << ((bin & 1) * 16));
    }
}

// ---------------- fold+transpose x -> fx[8][STRIDE]; also zero bin0 ----------------
__global__ __launch_bounds__(256) void foldx(const float* __restrict__ x, float* __restrict__ fx,
                                             uint4* __restrict__ zb)
{
    __shared__ float4 tile[1024];    // 256 rows x 16 floats
    const int tid = threadIdx.x;
    const int h0 = blockIdx.x * 256;
    for (int i = tid; i < 1024; i += 256) tile[i] = ((const float4*)x)[(size_t)h0*4 + i];
    __syncthreads();
    float4 a = tile[tid*4+0], b = tile[tid*4+1], c = tile[tid*4+2], d = tile[tid*4+3];
    const int h = h0 + tid;
    fx[(size_t)0*STRIDE + h] = a.x + a.y;
    fx[(size_t)1*STRIDE + h] = a.z + a.w;
    fx[(size_t)2*STRIDE + h] = b.x + b.y;
    fx[(size_t)3*STRIDE + h] = b.z + b.w;
    fx[(size_t)4*STRIDE + h] = c.x + c.y;
    fx[(size_t)5*STRIDE + h] = c.z + c.w;
    fx[(size_t)6*STRIDE + h] = d.x + d.y;
    fx[(size_t)7*STRIDE + h] = d.z + d.w;
    const uint4 z = make_uint4(0,0,0,0);
    for (int i = blockIdx.x*256 + tid; i < ZW/4; i += gridDim.x*256) zb[i] = z;
}

// ---------------- layer-0 conv+hist: float4 shifted window, 4 outputs/thread ----------------
#define C0CHUNK 8192             // 4 tiles of 2048; 33 chunks x 16 cols = 528 blocks (~2/CU)
__global__ __launch_bounds__(512) void conv0_lds(const float* __restrict__ fx, u32* __restrict__ H,
                                                 const float* __restrict__ w0, const float* __restrict__ b0)
{
    __shared__ u32 hist[NB/2];                 // 6 KB packed u16 pairs
    __shared__ __align__(16) float s0f[2148];  // window floats [t0-98, t0+2049]; 537 float4s
    __shared__ float sw[100];                  // sw[99] = 0 pad
    const int colv = blockIdx.y;               // 0..15 = o*8 + wp
    const int o = colv >> 3, wp = colv & 7;
    const int tid = threadIdx.x;
    const int p0 = blockIdx.x * C0CHUNK;
    const int p1 = min(p0 + C0CHUNK, 262242);
    if (p0 >= 262242) return;
    for (int i = tid; i < NB/2; i += 512) hist[i] = 0;
    if (tid < 99) sw[tid] = w0[o*99 + tid];
    if (tid == 99) sw[99] = 0.f;
    const float bias = 2.f * b0[o];            // fold doubles bias
    __syncthreads();
    const float* fc = fx + (size_t)wp * STRIDE;
    const float4* s4 = (const float4*)s0f;
    for (int t0 = p0; t0 < p1; t0 += 2048){
        for (int i = tid; i < 2148; i += 512){
            int h = t0 - 98 + i;
            s0f[i] = (h >= 0 && h < 262144) ? fc[h] : 0.f;
        }
        __syncthreads();
        float a0 = bias, a1 = bias, a2 = bias, a3 = bias;
        float4 c = s4[tid];
        #pragma unroll
        for (int jb = 0; jb < 25; jb++){
            float4 n = s4[tid + jb + 1];
            float w0_ = sw[4*jb+0], w1_ = sw[4*jb+1], w2_ = sw[4*jb+2], w3_ = sw[4*jb+3];
            a0 += w0_*c.x; a1 += w0_*c.y; a2 += w0_*c.z; a3 += w0_*c.w;
            a0 += w1_*c.y; a1 += w1_*c.z; a2 += w1_*c.w; a3 += w1_*n.x;
            a0 += w2_*c.z; a1 += w2_*c.w; a2 += w2_*n.x; a3 += w2_*n.y;
            a0 += w3_*c.w; a1 += w3_*n.x; a2 += w3_*n.y; a3 += w3_*n.z;   // sw[99]=0
            c = n;
        }
        int hp = t0 + tid*4;
        if (hp     < p1){ int b = bin_of(a0); atomicAdd(&hist[b>>1], 1u << ((b&1)*16)); }
        if (hp + 1 < p1){ int b = bin_of(a1); atomicAdd(&hist[b>>1], 1u << ((b&1)*16)); }
        if (hp + 2 < p1){ int b = bin_of(a2); atomicAdd(&hist[b>>1], 1u << ((b&1)*16)); }
        if (hp + 3 < p1){ int b = bin_of(a3); atomicAdd(&hist[b>>1], 1u << ((b&1)*16)); }
        __syncthreads();
    }
    u32* Hc = H + (size_t)colv * NB;
    for (int i = tid; i < NB/2; i += 512){
        u32 w = hist[i];
        if (w){
            u32 lo = w & 0xFFFFu, hi = w >> 16;
            if (lo) atomicAdd(&Hc[2*i],   lo);
            if (hi) atomicAdd(&Hc[2*i+1], hi);
        }
    }
}

// ---------------- K=9 conv+hist: float4 shifted window, 4 outputs/thread ----------------
#define C9CHUNK 8192             // 4 tiles of 2048 per block
template<int FOLDIN>
__global__ __launch_bounds__(512) void conv9_lds(
    const float* __restrict__ In, u32* __restrict__ H,
    const float* __restrict__ Wt, const float* __restrict__ Bs,
    int Hin, int Hout, int Wi, int Wo, float bscale)
{
    __shared__ u32 hist[NB/2];                 // 6 KB
    __shared__ __align__(16) float s0f[2056];  // window: logical float i = h - (t0-8), i in [0,2056)
    __shared__ __align__(16) float s1f[2056];
    const int colv = blockIdx.y;               // o*Wo + wp
    const int o = colv / Wo, wp = colv % Wo;
    const int tid = threadIdx.x;
    const int lane = tid & 63;
    const int p0 = blockIdx.x * C9CHUNK;
    const int p1 = min(p0 + C9CHUNK, Hout);
    if (p0 >= Hout) return;
    for (int i = tid; i < NB/2; i += 512) hist[i] = 0;
    float w0r[9], w1r[9];
    #pragma unroll
    for (int j = 0; j < 9; j++){ w0r[j] = Wt[(o*2)*9 + j]; w1r[j] = Wt[(o*2)*9 + 9 + j]; }
    const float bv = bscale * Bs[o];
    __syncthreads();
    const float* i00 = In + (size_t)(0*Wi + (FOLDIN ? 2*wp   : wp))*STRIDE;
    const float* i01 = In + (size_t)(0*Wi + (FOLDIN ? 2*wp+1 : wp))*STRIDE;
    const float* i10 = In + (size_t)(1*Wi + (FOLDIN ? 2*wp   : wp))*STRIDE;
    const float* i11 = In + (size_t)(1*Wi + (FOLDIN ? 2*wp+1 : wp))*STRIDE;
    const float4* s40 = (const float4*)s0f;
    const float4* s41 = (const float4*)s1f;
    for (int t0 = p0; t0 < p1; t0 += 2048){
        for (int i = tid; i < 2056; i += 512){
            int h = t0 - 8 + i;
            float v0 = 0.f, v1 = 0.f;
            if (h >= 0 && h < Hin){
                v0 = FOLDIN ? (i00[h] + i01[h]) : i00[h];
                v1 = FOLDIN ? (i10[h] + i11[h]) : i10[h];
            }
            s0f[i] = v0; s1f[i] = v1;
        }
        __syncthreads();
        // outputs hp = t0 + 4*tid + r (r=0..3); tap j reads logical float 4*tid + r + j
        float a0 = bv, a1 = bv, a2 = bv, a3 = bv;
        {   // channel 0 taps j=0..8 ascending (preserve original accumulation order)
            float4 X = s40[tid], Y = s40[tid+1], Z = s40[tid+2];
            a0 += w0r[0]*X.x; a1 += w0r[0]*X.y; a2 += w0r[0]*X.z; a3 += w0r[0]*X.w;
            a0 += w0r[1]*X.y; a1 += w0r[1]*X.z; a2 += w0r[1]*X.w; a3 += w0r[1]*Y.x;
            a0 += w0r[2]*X.z; a1 += w0r[2]*X.w; a2 += w0r[2]*Y.x; a3 += w0r[2]*Y.y;
            a0 += w0r[3]*X.w; a1 += w0r[3]*Y.x; a2 += w0r[3]*Y.y; a3 += w0r[3]*Y.z;
            a0 += w0r[4]*Y.x; a1 += w0r[4]*Y.y; a2 += w0r[4]*Y.z; a3 += w0r[4]*Y.w;
            a0 += w0r[5]*Y.y; a1 += w0r[5]*Y.z; a2 += w0r[5]*Y.w; a3 += w0r[5]*Z.x;
            a0 += w0r[6]*Y.z; a1 += w0r[6]*Y.w; a2 += w0r[6]*Z.x; a3 += w0r[6]*Z.y;
            a0 += w0r[7]*Y.w; a1 += w0r[7]*Z.x; a2 += w0r[7]*Z.y; a3 += w0r[7]*Z.z;
            a0 += w0r[8]*Z.x; a1 += w0r[8]*Z.y; a2 += w0r[8]*Z.z; a3 += w0r[8]*Z.w;
        }
        {   // then channel 1
            float4 X = s41[tid], Y = s41[tid+1], Z = s41[tid+2];
            a0 += w1r[0]*X.x; a1 += w1r[0]*X.y; a2 += w1r[0]*X.z; a3 += w1r[0]*X.w;
            a0 += w1r[1]*X.y; a1 += w1r[1]*X.z; a2 += w1r[1]*X.w; a3 += w1r[1]*Y.x;
            a0 += w1r[2]*X.z; a1 += w1r[2]*X.w; a2 += w1r[2]*Y.x; a3 += w1r[2]*Y.y;
            a0 += w1r[3]*X.w; a1 += w1r[3]*Y.x; a2 += w1r[3]*Y.y; a3 += w1r[3]*Y.z;
            a0 += w1r[4]*Y.x; a1 += w1r[4]*Y.y; a2 += w1r[4]*Y.z; a3 += w1r[4]*Y.w;
            a0 += w1r[5]*Y.y; a1 += w1r[5]*Y.z; a2 += w1r[5]*Y.w; a3 += w1r[5]*Z.x;
            a0 += w1r[6]*Y.z; a1 += w1r[6]*Y.w; a2 += w1r[6]*Z.x; a3 += w1r[6]*Z.y;
            a0 += w1r[7]*Y.w; a1 += w1r[7]*Z.x; a2 += w1r[7]*Z.y; a3 += w1r[7]*Z.z;
            a0 += w1r[8]*Z.x; a1 += w1r[8]*Z.y; a2 += w1r[8]*Z.z; a3 += w1r[8]*Z.w;
        }
        int hp = t0 + tid*4;
        lds_hist_dedup(hist, bin_of(a0), hp     < p1, lane);
        lds_hist_dedup(hist, bin_of(a1), hp + 1 < p1, lane);
        lds_hist_dedup(hist, bin_of(a2), hp + 2 < p1, lane);
        lds_hist_dedup(hist, bin_of(a3), hp + 3 < p1, lane);
        __syncthreads();
    }
    u32* Hc = H + (size_t)colv * NB;
    for (int i = tid; i < NB/2; i += 512){
        u32 w = hist[i];
        if (w){
            u32 lo = w & 0xFFFFu, hi = w >> 16;
            if (lo) atomicAdd(&Hc[2*i],   lo);
            if (hi) atomicAdd(&Hc[2*i+1], hi);
        }
    }
}

// ---------------- layer-19 conv+hist (K=358, 2->5ch; global dedup atomics) ----------------
template<int INC, int OUTC>
__global__ __launch_bounds__(256) void conv_hist_t(
    const float* __restrict__ In, u32* __restrict__ H,
    const float* __restrict__ Wt, const float* __restrict__ Bs,
    int Hin, int Hout, int K, int pad, int Wi, int Wo, int foldIn, float bscale)
{
    __shared__ float sIn[INC][613];
    __shared__ float sW[OUTC*INC*358];
    const int wp = blockIdx.y;
    const int h0 = blockIdx.x * 256;
    const int tid = threadIdx.x;
    const int lane = tid & 63;
    const int tl = 256 + K - 1;
    for (int t = tid; t < INC*tl; t += 256){
        int c = t / tl, r = t - c*tl;
        int h = h0 - pad + r;
        float v = 0.f;
        if (h >= 0 && h < Hin){
            if (foldIn) v = In[(size_t)(c*Wi + 2*wp)*STRIDE + h] + In[(size_t)(c*Wi + 2*wp + 1)*STRIDE + h];
            else        v = In[(size_t)(c*Wi + wp)*STRIDE + h];
        }
        sIn[c][r] = v;
    }
    for (int t = tid; t < OUTC*INC*K; t += 256) sW[t] = Wt[t];
    __syncthreads();
    int hp = h0 + tid;
    bool valid = (hp < Hout);
    float acc[OUTC];
    #pragma unroll
    for (int o = 0; o < OUTC; o++) acc[o] = bscale * Bs[o];
    for (int c = 0; c < INC; c++){
        for (int j = 0; j < K; j++){
            float xv = sIn[c][tid + j];
            #pragma unroll
            for (int o = 0; o < OUTC; o++) acc[o] += sW[(o*INC + c)*K + j] * xv;
        }
    }
    #pragma unroll
    for (int o = 0; o < OUTC; o++)
        hist_add(H + (size_t)(o*Wo + wp)*NB, bin_of(acc[o]), valid, lane);
}

// ---------------- fused scan + reconstruct (binary search PER RUN) + next-bin zeroing ----------------
__global__ __launch_bounds__(1024) void scan_fill(
    const u32* __restrict__ H, float* __restrict__ dst, const float* __restrict__ alphaPtr,
    int kOut, int dup, int act, uint4* __restrict__ zb)
{
    __shared__ u32 pre[NB];          // 12 KB inclusive prefix
    __shared__ u32 warr[16];
    const int col = blockIdx.y;
    const int tid = threadIdx.x;
    const int lane = tid & 63, wv = tid >> 6;
    const u32* Hc = H + (size_t)col * NB;
    for (int i = tid; i < NB; i += 1024) pre[i] = Hc[i];
    __syncthreads();
    const int base = tid * 3;
    u32 v[3]; u32 s = 0;
    #pragma unroll
    for (int i = 0; i < 3; i++){ v[i] = pre[base + i]; s += v[i]; v[i] = s; }
    u32 ss = s;
    #pragma unroll
    for (int d = 1; d < 64; d <<= 1){
        u32 t = __shfl_up(ss, d);
        if (lane >= d) ss += t;
    }
    if (lane == 63) warr[wv] = ss;
    __syncthreads();
    u32 wb = 0;
    #pragma unroll
    for (int w = 0; w < 16; w++) wb += (w < wv) ? warr[w] : 0u;
    u32 excl = wb + ss - s;
    #pragma unroll
    for (int i = 0; i < 3; i++) pre[base + i] = v[i] + excl;
    __syncthreads();

    const int S  = gridDim.x;
    const int nr = kOut / dup;
    const int per = (nr + S*1024 - 1) / (S*1024);
    int i = (blockIdx.x*1024 + tid) * per;
    const int i1 = min(i + per, nr);
    float* d = dst + (size_t)col * STRIDE;
    const float alpha = alphaPtr[0];
    int lo0 = 0;                                  // monotone lower bound across runs
    while (i < i1){
        int lo = lo0, hi = NB - 1;                // smallest bin with pre[bin] > i
        while (lo < hi){ int m = (lo + hi) >> 1; if (pre[m] > (u32)i) hi = m; else lo = m + 1; }
        float vv = bin_val(lo);
        if (act == ACT_PRELU)      vv = (vv >= 0.f) ? vv : alpha * vv;
        else if (act == ACT_RELU)  vv = (vv > 0.f) ? vv : 0.f;
        else                       vv = (vv > 0.f) ? vv : expm1f(vv);
        int e = (int)min((u32)i1, pre[lo]);
        for (; i < e; i++){
            int bse = i * dup;
            for (int dd = 0; dd < dup; dd++) d[bse + dd] = vv;
        }
        lo0 = lo + 1;                             // next rank's bin is strictly above lo
    }
    // zero the other bin buffer for the next layer (vectorized)
    const uint4 z = make_uint4(0,0,0,0);
    int lin = (blockIdx.y * gridDim.x + blockIdx.x) * 1024 + tid;
    int tot = gridDim.x * gridDim.y * 1024;
    for (int q = lin; q < ZW/4; q += tot) zb[q] = z;
}

// ---------------- FC: 1000 logits, one block each; then log_softmax ----------------
__global__ __launch_bounds__(256) void fc_dot(const float* __restrict__ A, const float* __restrict__ Wfc,
                                              const float* __restrict__ bfc, float* __restrict__ logits)
{
    const int t = blockIdx.x;            // 0..999
    const int o = t / 200, j = t - o*200;
    const float* wrow = Wfc + (size_t)j*1600;
    float acc = 0.f;
    for (int q = threadIdx.x; q < 1600; q += 256){
        int p = q >> 1, wq = q & 1;
        acc += wrow[q] * A[(size_t)(o*2 + wq)*STRIDE + p];
    }
    __shared__ float red[256];
    red[threadIdx.x] = acc;
    __syncthreads();
    for (int s = 128; s > 0; s >>= 1){
        if (threadIdx.x < s) red[threadIdx.x] += red[threadIdx.x + s];
        __syncthreads();
    }
    if (threadIdx.x == 0) logits[t] = red[0] + bfc[j];
}

__global__ __launch_bounds__(1024) void lsm(const float* __restrict__ logits, float* __restrict__ out)
{
    const int tid = threadIdx.x;
    __shared__ float red[1024];
    float lg = (tid < 1000) ? logits[tid] : -INFINITY;
    red[tid] = lg;
    __syncthreads();
    for (int s = 512; s > 0; s >>= 1){
        if (tid < s) red[tid] = fmaxf(red[tid], red[tid + s]);
        __syncthreads();
    }
    float m = red[0];
    __syncthreads();
    red[tid] = (tid < 1000) ? expf(lg - m) : 0.f;
    __syncthreads();
    for (int s = 512; s > 0; s >>= 1){
        if (tid < s) red[tid] += red[tid + s];
        __syncthreads();
    }
    float lse = logf(red[0]);
    if (tid < 1000) out[tid] = lg - m - lse;
}

extern "C" void kernel_launch(void* const* d_in, const int* in_sizes, int n_in,
                              void* d_out, int out_size, void* d_ws, size_t ws_size,
                              hipStream_t stream)
{
    (void)in_sizes; (void)n_in; (void)out_size;
    const size_t need = (size_t)24*STRIDE*4 + (size_t)2*ZW*4 + 4096;
    if (ws_size < need) return;

    const float* x   = (const float*)d_in[0];
    const float* w0  = (const float*)d_in[1];
    const float* b0  = (const float*)d_in[2];
    const float* wm  = (const float*)d_in[3];
    const float* bm  = (const float*)d_in[4];
    const float* w18 = (const float*)d_in[5];
    const float* b18 = (const float*)d_in[6];
    const float* w19 = (const float*)d_in[7];
    const float* b19 = (const float*)d_in[8];
    const float* a1  = (const float*)d_in[9];
    const float* a2  = (const float*)d_in[10];
    const float* Wfc = (const float*)d_in[11];
    const float* bfc = (const float*)d_in[12];

    float* b1   = (float*)d_ws;
    float* fx   = b1 + (size_t)16*STRIDE;
    u32*  bin0  = (u32*)(fx + (size_t)8*STRIDE);
    u32*  bin1  = bin0 + (size_t)ZW;
    float* logits = (float*)(bin1 + (size_t)ZW);

    u32* cur = bin0;
    u32* nxt = bin1;

    // fold+transpose x; zero bin0
    foldx<<<1024, 256, 0, stream>>>(x, fx, (uint4*)cur);

    // ---- layer 0: conv(99, pad 98) -> fold(x2 dup) -> kmax 262144 -> PReLU(a1) ----
    conv0_lds<<<dim3(33, 16), 512, 0, stream>>>(fx, cur, w0, b0);
    scan_fill<<<dim3(16, 16), 1024, 0, stream>>>(cur, b1, a1, 262144, 2, ACT_PRELU, (uint4*)nxt);
    { u32* t = cur; cur = nxt; nxt = t; }
    int Hin = 262144;

    // ---- layers 1..17: conv(9, pad 8) -> kmax -> PReLU(a2)/ReLU ----
    static const int ks[17] = {249036,235929,222822,209715,196608,183500,170393,157286,
                               144179,131072,117964,104857,91750,78643,65536,52428,39321};
    for (int i = 0; i < 17; i++){
        int Hout = Hin + 8;
        int nch = (Hout + C9CHUNK - 1) / C9CHUNK;
        conv9_lds<0><<<dim3(nch, 16), 512, 0, stream>>>(
            b1, cur, wm + (size_t)i*36, bm + (size_t)i*2, Hin, Hout, 8, 8, 1.f);
        scan_fill<<<dim3(16, 16), 1024, 0, stream>>>(cur, b1, a2, ks[i], 1,
                                                     (i == 0) ? ACT_PRELU : ACT_RELU, (uint4*)nxt);
        { u32* t = cur; cur = nxt; nxt = t; }
        Hin = ks[i];
    }

    // ---- layer 18: conv(9) -> fold(widths 8->4, x2 dup) -> kmax 26214 -> ELU ----
    {
        int Hout = Hin + 8;   // 39329
        int nch = (Hout + C9CHUNK - 1) / C9CHUNK;
        conv9_lds<1><<<dim3(nch, 8), 512, 0, stream>>>(
            b1, cur, w18, b18, Hin, Hout, 8, 4, 2.f);
        scan_fill<<<dim3(4, 8), 1024, 0, stream>>>(cur, b1, a2, 26214, 2, ACT_ELU, (uint4*)nxt);
        { u32* t = cur; cur = nxt; nxt = t; }
        Hin = 26214;
    }

    // ---- layer 19: conv(358, pad 357, 2->5ch) -> fold(widths 4->2, x5 dup) -> kmax 800 -> ELU ----
    {
        int Hout = Hin + 714 - 358 + 1;   // 26571
        conv_hist_t<2,5><<<dim3((Hout + 255)/256, 2), 256, 0, stream>>>(
            b1, cur, w19, b19, Hin, Hout, 358, 357, 4, 2, 1, 2.f);
        scan_fill<<<dim3(1, 10), 1024, 0, stream>>>(cur, b1, a2, 800, 5, ACT_ELU, (uint4*)nxt);
    }

    // ---- FC + log_softmax ----
    fc_dot<<<1000, 256, 0, stream>>>(b1, Wfc, bfc, logits);
    lsm<<<1, 1024, 0, stream>>>(logits, (float*)d_out);
}

// Round 28
// 615.837 us; speedup vs baseline: 4.4491x; 1.0336x over previous
//
#include <hip/hip_runtime.h>
#include <math.h>

typedef unsigned int u32;
typedef unsigned long long u64;

#define STRIDE 262656          // per-column stride in floats
#define KSHIFT 18
#define KROUND 0x20000u
#define BAND   768             // 24 exponents x 32 mantissa steps per sign
#define NB     1536            // bins per column
#define PA18   0xE20u
#define NA18   0x2EE0u
#define NCOLS  16
#define ZW     (NB*NCOLS)      // u32 words in one bin buffer
#define ACT_PRELU 0
#define ACT_RELU  1
#define ACT_ELU   2

__device__ __forceinline__ float k2f(u32 k){
    u32 u = (k & 0x80000000u) ? k : (k ^ 0x7FFFFFFFu);
    return __uint_as_float(u);
}
__device__ __forceinline__ int bin_of(float v){
    float av = fabsf(v);
    av = fminf(fmaxf(av, 0.00390625f), 65535.96875f);
    u32 u = __float_as_uint(av);
    if (v < 0.f){
        u32 k = 0x80000000u | u;
        int b = (int)(((k + KROUND) >> KSHIFT) - NA18);
        b = b < 0 ? 0 : (b > BAND-1 ? BAND-1 : b);
        return BAND + b;
    } else {
        u32 k = u ^ 0x7FFFFFFFu;
        int b = (int)(((k + KROUND) >> KSHIFT) - PA18);
        b = b < 0 ? 0 : (b > BAND-1 ? BAND-1 : b);
        return b;
    }
}
__device__ __forceinline__ float bin_val(int bin){
    u32 k18 = (bin < BAND) ? ((u32)bin + PA18) : ((u32)(bin - BAND) + NA18);
    return k2f(k18 << KSHIFT);
}

// wave run-length dedup -> one GLOBAL atomic per run per wave
__device__ __forceinline__ void hist_add(u32* __restrict__ Hc, int bin, bool valid, int lane){
    u32 bn = valid ? (u32)bin : 0xFFFFFFFFu;
    u32 prev = __shfl_up(bn, 1);
    bool diff = (lane == 0) || (prev != bn);
    u64 m = __ballot(diff || !valid);
    if (valid && diff){
        u64 above = m & ~((2ull << lane) - 1ull);
        int nxt = above ? (__ffsll((unsigned long long)above) - 1) : 64;
        atomicAdd(&Hc[bin], (u32)(nxt - lane));
    }
}

// wave run-length dedup -> one packed-u16 LDS atomic per run per wave
__device__ __forceinline__ void lds_hist_dedup(u32* __restrict__ hist, int bin, bool valid, int lane){
    u32 bn = valid ? (u32)bin : 0xFFFFFFFFu;
    u32 prev = __shfl_up(bn, 1);
    bool diff = (lane == 0) || (prev != bn);
    u64 m = __ballot(diff || !valid);
    if (valid && diff){
        u64 above = m & ~((2ull << lane) - 1ull);
        int nxt = above ? (__ffsll((unsigned long long)above) - 1) : 64;
        u32 cnt = (u32)(nxt - lane);
        atomicAdd(&hist[bin >> 1], cnt << ((bin & 1) * 16));
    }
}

// ---------------- fold+transpose x -> fx[8][STRIDE]; also zero bin0 ----------------
__global__ __launch_bounds__(256) void foldx(const float* __restrict__ x, float* __restrict__ fx,
                                             uint4* __restrict__ zb)
{
    __shared__ float4 tile[1024];    // 256 rows x 16 floats
    const int tid = threadIdx.x;
    const int h0 = blockIdx.x * 256;
    for (int i = tid; i < 1024; i += 256) tile[i] = ((const float4*)x)[(size_t)h0*4 + i];
    __syncthreads();
    float4 a = tile[tid*4+0], b = tile[tid*4+1], c = tile[tid*4+2], d = tile[tid*4+3];
    const int h = h0 + tid;
    fx[(size_t)0*STRIDE + h] = a.x + a.y;
    fx[(size_t)1*STRIDE + h] = a.z + a.w;
    fx[(size_t)2*STRIDE + h] = b.x + b.y;
    fx[(size_t)3*STRIDE + h] = b.z + b.w;
    fx[(size_t)4*STRIDE + h] = c.x + c.y;
    fx[(size_t)5*STRIDE + h] = c.z + c.w;
    fx[(size_t)6*STRIDE + h] = d.x + d.y;
    fx[(size_t)7*STRIDE + h] = d.z + d.w;
    const uint4 z = make_uint4(0,0,0,0);
    for (int i = blockIdx.x*256 + tid; i < ZW/4; i += gridDim.x*256) zb[i] = z;
}

// ---------------- layer-0 conv+hist: float4 shifted window, 4 outputs/thread ----------------
#define C0CHUNK 8192             // 4 tiles of 2048; 33 chunks x 16 cols = 528 blocks (~2/CU)
__global__ __launch_bounds__(512) void conv0_lds(const float* __restrict__ fx, u32* __restrict__ H,
                                                 const float* __restrict__ w0, const float* __restrict__ b0)
{
    __shared__ u32 hist[NB/2];                 // 3 KB packed u16 pairs
    __shared__ __align__(16) float s0f[2148];  // window floats [t0-98, t0+2049]; 537 float4s
    __shared__ float sw[100];                  // sw[99] = 0 pad
    const int colv = blockIdx.y;               // 0..15 = o*8 + wp
    const int o = colv >> 3, wp = colv & 7;
    const int tid = threadIdx.x;
    const int p0 = blockIdx.x * C0CHUNK;
    const int p1 = min(p0 + C0CHUNK, 262242);
    if (p0 >= 262242) return;
    for (int i = tid; i < NB/2; i += 512) hist[i] = 0;
    if (tid < 99) sw[tid] = w0[o*99 + tid];
    if (tid == 99) sw[99] = 0.f;
    const float bias = 2.f * b0[o];            // fold doubles bias
    __syncthreads();
    const float* fc = fx + (size_t)wp * STRIDE;
    const float4* s4 = (const float4*)s0f;
    for (int t0 = p0; t0 < p1; t0 += 2048){
        for (int i = tid; i < 2148; i += 512){
            int h = t0 - 98 + i;
            s0f[i] = (h >= 0 && h < 262144) ? fc[h] : 0.f;
        }
        __syncthreads();
        float a0 = bias, a1 = bias, a2 = bias, a3 = bias;
        float4 c = s4[tid];
        #pragma unroll
        for (int jb = 0; jb < 25; jb++){
            float4 n = s4[tid + jb + 1];
            float w0_ = sw[4*jb+0], w1_ = sw[4*jb+1], w2_ = sw[4*jb+2], w3_ = sw[4*jb+3];
            a0 += w0_*c.x; a1 += w0_*c.y; a2 += w0_*c.z; a3 += w0_*c.w;
            a0 += w1_*c.y; a1 += w1_*c.z; a2 += w1_*c.w; a3 += w1_*n.x;
            a0 += w2_*c.z; a1 += w2_*c.w; a2 += w2_*n.x; a3 += w2_*n.y;
            a0 += w3_*c.w; a1 += w3_*n.x; a2 += w3_*n.y; a3 += w3_*n.z;   // sw[99]=0
            c = n;
        }
        int hp = t0 + tid*4;
        if (hp     < p1){ int b = bin_of(a0); atomicAdd(&hist[b>>1], 1u << ((b&1)*16)); }
        if (hp + 1 < p1){ int b = bin_of(a1); atomicAdd(&hist[b>>1], 1u << ((b&1)*16)); }
        if (hp + 2 < p1){ int b = bin_of(a2); atomicAdd(&hist[b>>1], 1u << ((b&1)*16)); }
        if (hp + 3 < p1){ int b = bin_of(a3); atomicAdd(&hist[b>>1], 1u << ((b&1)*16)); }
        __syncthreads();
    }
    u32* Hc = H + (size_t)colv * NB;
    for (int i = tid; i < NB/2; i += 512){
        u32 w = hist[i];
        if (w){
            u32 lo = w & 0xFFFFu, hi = w >> 16;
            if (lo) atomicAdd(&Hc[2*i],   lo);
            if (hi) atomicAdd(&Hc[2*i+1], hi);
        }
    }
}

// ---------------- K=9 conv+hist: float4 shifted window, 4 outputs/thread ----------------
#define C9CHUNK 8192             // 4 tiles of 2048 per block
template<int FOLDIN>
__global__ __launch_bounds__(512) void conv9_lds(
    const float* __restrict__ In, u32* __restrict__ H,
    const float* __restrict__ Wt, const float* __restrict__ Bs,
    int Hin, int Hout, int Wi, int Wo, float bscale)
{
    __shared__ u32 hist[NB/2];                 // 3 KB
    __shared__ __align__(16) float s0f[2056];  // window: logical float i = h - (t0-8), i in [0,2056)
    __shared__ __align__(16) float s1f[2056];
    const int colv = blockIdx.y;               // o*Wo + wp
    const int o = colv / Wo, wp = colv % Wo;
    const int tid = threadIdx.x;
    const int lane = tid & 63;
    const int p0 = blockIdx.x * C9CHUNK;
    const int p1 = min(p0 + C9CHUNK, Hout);
    if (p0 >= Hout) return;
    for (int i = tid; i < NB/2; i += 512) hist[i] = 0;
    float w0r[9], w1r[9];
    #pragma unroll
    for (int j = 0; j < 9; j++){ w0r[j] = Wt[(o*2)*9 + j]; w1r[j] = Wt[(o*2)*9 + 9 + j]; }
    const float bv = bscale * Bs[o];
    __syncthreads();
    const float* i00 = In + (size_t)(0*Wi + (FOLDIN ? 2*wp   : wp))*STRIDE;
    const float* i01 = In + (size_t)(0*Wi + (FOLDIN ? 2*wp+1 : wp))*STRIDE;
    const float* i10 = In + (size_t)(1*Wi + (FOLDIN ? 2*wp   : wp))*STRIDE;
    const float* i11 = In + (size_t)(1*Wi + (FOLDIN ? 2*wp+1 : wp))*STRIDE;
    const float4* s40 = (const float4*)s0f;
    const float4* s41 = (const float4*)s1f;
    for (int t0 = p0; t0 < p1; t0 += 2048){
        for (int i = tid; i < 2056; i += 512){
            int h = t0 - 8 + i;
            float v0 = 0.f, v1 = 0.f;
            if (h >= 0 && h < Hin){
                v0 = FOLDIN ? (i00[h] + i01[h]) : i00[h];
                v1 = FOLDIN ? (i10[h] + i11[h]) : i10[h];
            }
            s0f[i] = v0; s1f[i] = v1;
        }
        __syncthreads();
        // outputs hp = t0 + 4*tid + r (r=0..3); tap j reads logical float 4*tid + r + j
        float a0 = bv, a1 = bv, a2 = bv, a3 = bv;
        {   // channel 0 taps j=0..8 ascending (preserve original accumulation order)
            float4 X = s40[tid], Y = s40[tid+1], Z = s40[tid+2];
            a0 += w0r[0]*X.x; a1 += w0r[0]*X.y; a2 += w0r[0]*X.z; a3 += w0r[0]*X.w;
            a0 += w0r[1]*X.y; a1 += w0r[1]*X.z; a2 += w0r[1]*X.w; a3 += w0r[1]*Y.x;
            a0 += w0r[2]*X.z; a1 += w0r[2]*X.w; a2 += w0r[2]*Y.x; a3 += w0r[2]*Y.y;
            a0 += w0r[3]*X.w; a1 += w0r[3]*Y.x; a2 += w0r[3]*Y.y; a3 += w0r[3]*Y.z;
            a0 += w0r[4]*Y.x; a1 += w0r[4]*Y.y; a2 += w0r[4]*Y.z; a3 += w0r[4]*Y.w;
            a0 += w0r[5]*Y.y; a1 += w0r[5]*Y.z; a2 += w0r[5]*Y.w; a3 += w0r[5]*Z.x;
            a0 += w0r[6]*Y.z; a1 += w0r[6]*Y.w; a2 += w0r[6]*Z.x; a3 += w0r[6]*Z.y;
            a0 += w0r[7]*Y.w; a1 += w0r[7]*Z.x; a2 += w0r[7]*Z.y; a3 += w0r[7]*Z.z;
            a0 += w0r[8]*Z.x; a1 += w0r[8]*Z.y; a2 += w0r[8]*Z.z; a3 += w0r[8]*Z.w;
        }
        {   // then channel 1
            float4 X = s41[tid], Y = s41[tid+1], Z = s41[tid+2];
            a0 += w1r[0]*X.x; a1 += w1r[0]*X.y; a2 += w1r[0]*X.z; a3 += w1r[0]*X.w;
            a0 += w1r[1]*X.y; a1 += w1r[1]*X.z; a2 += w1r[1]*X.w; a3 += w1r[1]*Y.x;
            a0 += w1r[2]*X.z; a1 += w1r[2]*X.w; a2 += w1r[2]*Y.x; a3 += w1r[2]*Y.y;
            a0 += w1r[3]*X.w; a1 += w1r[3]*Y.x; a2 += w1r[3]*Y.y; a3 += w1r[3]*Y.z;
            a0 += w1r[4]*Y.x; a1 += w1r[4]*Y.y; a2 += w1r[4]*Y.z; a3 += w1r[4]*Y.w;
            a0 += w1r[5]*Y.y; a1 += w1r[5]*Y.z; a2 += w1r[5]*Y.w; a3 += w1r[5]*Z.x;
            a0 += w1r[6]*Y.z; a1 += w1r[6]*Y.w; a2 += w1r[6]*Z.x; a3 += w1r[6]*Z.y;
            a0 += w1r[7]*Y.w; a1 += w1r[7]*Z.x; a2 += w1r[7]*Z.y; a3 += w1r[7]*Z.z;
            a0 += w1r[8]*Z.x; a1 += w1r[8]*Z.y; a2 += w1r[8]*Z.z; a3 += w1r[8]*Z.w;
        }
        int hp = t0 + tid*4;
        lds_hist_dedup(hist, bin_of(a0), hp     < p1, lane);
        lds_hist_dedup(hist, bin_of(a1), hp + 1 < p1, lane);
        lds_hist_dedup(hist, bin_of(a2), hp + 2 < p1, lane);
        lds_hist_dedup(hist, bin_of(a3), hp + 3 < p1, lane);
        __syncthreads();
    }
    u32* Hc = H + (size_t)colv * NB;
    for (int i = tid; i < NB/2; i += 512){
        u32 w = hist[i];
        if (w){
            u32 lo = w & 0xFFFFu, hi = w >> 16;
            if (lo) atomicAdd(&Hc[2*i],   lo);
            if (hi) atomicAdd(&Hc[2*i+1], hi);
        }
    }
}

// ---------------- layer-19 conv+hist (K=358, 2->5ch; global dedup atomics) ----------------
template<int INC, int OUTC>
__global__ __launch_bounds__(256) void conv_hist_t(
    const float* __restrict__ In, u32* __restrict__ H,
    const float* __restrict__ Wt, const float* __restrict__ Bs,
    int Hin, int Hout, int K, int pad, int Wi, int Wo, int foldIn, float bscale)
{
    __shared__ float sIn[INC][613];
    __shared__ float sW[OUTC*INC*358];
    const int wp = blockIdx.y;
    const int h0 = blockIdx.x * 256;
    const int tid = threadIdx.x;
    const int lane = tid & 63;
    const int tl = 256 + K - 1;
    for (int t = tid; t < INC*tl; t += 256){
        int c = t / tl, r = t - c*tl;
        int h = h0 - pad + r;
        float v = 0.f;
        if (h >= 0 && h < Hin){
            if (foldIn) v = In[(size_t)(c*Wi + 2*wp)*STRIDE + h] + In[(size_t)(c*Wi + 2*wp + 1)*STRIDE + h];
            else        v = In[(size_t)(c*Wi + wp)*STRIDE + h];
        }
        sIn[c][r] = v;
    }
    for (int t = tid; t < OUTC*INC*K; t += 256) sW[t] = Wt[t];
    __syncthreads();
    int hp = h0 + tid;
    bool valid = (hp < Hout);
    float acc[OUTC];
    #pragma unroll
    for (int o = 0; o < OUTC; o++) acc[o] = bscale * Bs[o];
    for (int c = 0; c < INC; c++){
        for (int j = 0; j < K; j++){
            float xv = sIn[c][tid + j];
            #pragma unroll
            for (int o = 0; o < OUTC; o++) acc[o] += sW[(o*INC + c)*K + j] * xv;
        }
    }
    #pragma unroll
    for (int o = 0; o < OUTC; o++)
        hist_add(H + (size_t)(o*Wo + wp)*NB, bin_of(acc[o]), valid, lane);
}

// ---------------- fused scan + reconstruct (binary search PER RUN) + next-bin zeroing ----------------
__global__ __launch_bounds__(1024) void scan_fill(
    const u32* __restrict__ H, float* __restrict__ dst, const float* __restrict__ alphaPtr,
    int kOut, int dup, int act, uint4* __restrict__ zb)
{
    __shared__ u32 pre[NB];          // 6 KB inclusive prefix
    __shared__ u32 warr[16];
    const int col = blockIdx.y;
    const int tid = threadIdx.x;
    const int lane = tid & 63, wv = tid >> 6;
    const u32* Hc = H + (size_t)col * NB;
    for (int i = tid; i < NB; i += 1024) pre[i] = Hc[i];
    __syncthreads();
    // threads 0..511 own 3 bins each (512*3 = 1536); upper half contributes 0
    const int base = tid * 3;
    u32 v[3]; u32 s = 0;
    if (tid < 512){
        #pragma unroll
        for (int i = 0; i < 3; i++){ v[i] = pre[base + i]; s += v[i]; v[i] = s; }
    }
    u32 ss = s;
    #pragma unroll
    for (int d = 1; d < 64; d <<= 1){
        u32 t = __shfl_up(ss, d);
        if (lane >= d) ss += t;
    }
    if (lane == 63) warr[wv] = ss;
    __syncthreads();
    u32 wb = 0;
    #pragma unroll
    for (int w = 0; w < 16; w++) wb += (w < wv) ? warr[w] : 0u;
    u32 excl = wb + ss - s;
    if (tid < 512){
        #pragma unroll
        for (int i = 0; i < 3; i++) pre[base + i] = v[i] + excl;
    }
    __syncthreads();

    const int S  = gridDim.x;
    const int nr = kOut / dup;
    const int per = (nr + S*1024 - 1) / (S*1024);
    int i = (blockIdx.x*1024 + tid) * per;
    const int i1 = min(i + per, nr);
    float* d = dst + (size_t)col * STRIDE;
    const float alpha = alphaPtr[0];
    int lo0 = 0;                                  // monotone lower bound across runs
    while (i < i1){
        int lo = lo0, hi = NB - 1;                // smallest bin with pre[bin] > i
        while (lo < hi){ int m = (lo + hi) >> 1; if (pre[m] > (u32)i) hi = m; else lo = m + 1; }
        float vv = bin_val(lo);
        if (act == ACT_PRELU)      vv = (vv >= 0.f) ? vv : alpha * vv;
        else if (act == ACT_RELU)  vv = (vv > 0.f) ? vv : 0.f;
        else                       vv = (vv > 0.f) ? vv : expm1f(vv);
        int e = (int)min((u32)i1, pre[lo]);
        for (; i < e; i++){
            int bse = i * dup;
            for (int dd = 0; dd < dup; dd++) d[bse + dd] = vv;
        }
        lo0 = lo + 1;                             // next rank's bin is strictly above lo
    }
    // zero the other bin buffer for the next layer (vectorized)
    const uint4 z = make_uint4(0,0,0,0);
    int lin = (blockIdx.y * gridDim.x + blockIdx.x) * 1024 + tid;
    int tot = gridDim.x * gridDim.y * 1024;
    for (int q = lin; q < ZW/4; q += tot) zb[q] = z;
}

// ---------------- FC: 1000 logits, one block each; then log_softmax ----------------
__global__ __launch_bounds__(256) void fc_dot(const float* __restrict__ A, const float* __restrict__ Wfc,
                                              const float* __restrict__ bfc, float* __restrict__ logits)
{
    const int t = blockIdx.x;            // 0..999
    const int o = t / 200, j = t - o*200;
    const float* wrow = Wfc + (size_t)j*1600;
    float acc = 0.f;
    for (int q = threadIdx.x; q < 1600; q += 256){
        int p = q >> 1, wq = q & 1;
        acc += wrow[q] * A[(size_t)(o*2 + wq)*STRIDE + p];
    }
    __shared__ float red[256];
    red[threadIdx.x] = acc;
    __syncthreads();
    for (int s = 128; s > 0; s >>= 1){
        if (threadIdx.x < s) red[threadIdx.x] += red[threadIdx.x + s];
        __syncthreads();
    }
    if (threadIdx.x == 0) logits[t] = red[0] + bfc[j];
}

__global__ __launch_bounds__(1024) void lsm(const float* __restrict__ logits, float* __restrict__ out)
{
    const int tid = threadIdx.x;
    __shared__ float red[1024];
    float lg = (tid < 1000) ? logits[tid] : -INFINITY;
    red[tid] = lg;
    __syncthreads();
    for (int s = 512; s > 0; s >>= 1){
        if (tid < s) red[tid] = fmaxf(red[tid], red[tid + s]);
        __syncthreads();
    }
    float m = red[0];
    __syncthreads();
    red[tid] = (tid < 1000) ? expf(lg - m) : 0.f;
    __syncthreads();
    for (int s = 512; s > 0; s >>= 1){
        if (tid < s) red[tid] += red[tid + s];
        __syncthreads();
    }
    float lse = logf(red[0]);
    if (tid < 1000) out[tid] = lg - m - lse;
}

extern "C" void kernel_launch(void* const* d_in, const int* in_sizes, int n_in,
                              void* d_out, int out_size, void* d_ws, size_t ws_size,
                              hipStream_t stream)
{
    (void)in_sizes; (void)n_in; (void)out_size;
    const size_t need = (size_t)24*STRIDE*4 + (size_t)2*ZW*4 + 4096;
    if (ws_size < need) return;

    const float* x   = (const float*)d_in[0];
    const float* w0  = (const float*)d_in[1];
    const float* b0  = (const float*)d_in[2];
    const float* wm  = (const float*)d_in[3];
    const float* bm  = (const float*)d_in[4];
    const float* w18 = (const float*)d_in[5];
    const float* b18 = (const float*)d_in[6];
    const float* w19 = (const float*)d_in[7];
    const float* b19 = (const float*)d_in[8];
    const float* a1  = (const float*)d_in[9];
    const float* a2  = (const float*)d_in[10];
    const float* Wfc = (const float*)d_in[11];
    const float* bfc = (const float*)d_in[12];

    float* b1   = (float*)d_ws;
    float* fx   = b1 + (size_t)16*STRIDE;
    u32*  bin0  = (u32*)(fx + (size_t)8*STRIDE);
    u32*  bin1  = bin0 + (size_t)ZW;
    float* logits = (float*)(bin1 + (size_t)ZW);

    u32* cur = bin0;
    u32* nxt = bin1;

    // fold+transpose x; zero bin0
    foldx<<<1024, 256, 0, stream>>>(x, fx, (uint4*)cur);

    // ---- layer 0: conv(99, pad 98) -> fold(x2 dup) -> kmax 262144 -> PReLU(a1) ----
    conv0_lds<<<dim3(33, 16), 512, 0, stream>>>(fx, cur, w0, b0);
    scan_fill<<<dim3(16, 16), 1024, 0, stream>>>(cur, b1, a1, 262144, 2, ACT_PRELU, (uint4*)nxt);
    { u32* t = cur; cur = nxt; nxt = t; }
    int Hin = 262144;

    // ---- layers 1..17: conv(9, pad 8) -> kmax -> PReLU(a2)/ReLU ----
    static const int ks[17] = {249036,235929,222822,209715,196608,183500,170393,157286,
                               144179,131072,117964,104857,91750,78643,65536,52428,39321};
    for (int i = 0; i < 17; i++){
        int Hout = Hin + 8;
        int nch = (Hout + C9CHUNK - 1) / C9CHUNK;
        conv9_lds<0><<<dim3(nch, 16), 512, 0, stream>>>(
            b1, cur, wm + (size_t)i*36, bm + (size_t)i*2, Hin, Hout, 8, 8, 1.f);
        scan_fill<<<dim3(16, 16), 1024, 0, stream>>>(cur, b1, a2, ks[i], 1,
                                                     (i == 0) ? ACT_PRELU : ACT_RELU, (uint4*)nxt);
        { u32* t = cur; cur = nxt; nxt = t; }
        Hin = ks[i];
    }

    // ---- layer 18: conv(9) -> fold(widths 8->4, x2 dup) -> kmax 26214 -> ELU ----
    {
        int Hout = Hin + 8;   // 39329
        int nch = (Hout + C9CHUNK - 1) / C9CHUNK;
        conv9_lds<1><<<dim3(nch, 8), 512, 0, stream>>>(
            b1, cur, w18, b18, Hin, Hout, 8, 4, 2.f);
        scan_fill<<<dim3(4, 8), 1024, 0, stream>>>(cur, b1, a2, 26214, 2, ACT_ELU, (uint4*)nxt);
        { u32* t = cur; cur = nxt; nxt = t; }
        Hin = 26214;
    }

    // ---- layer 19: conv(358, pad 357, 2->5ch) -> fold(widths 4->2, x5 dup) -> kmax 800 -> ELU ----
    {
        int Hout = Hin + 714 - 358 + 1;   // 26571
        conv_hist_t<2,5><<<dim3((Hout + 255)/256, 2), 256, 0, stream>>>(
            b1, cur, w19, b19, Hin, Hout, 358, 357, 4, 2, 1, 2.f);
        scan_fill<<<dim3(1, 10), 1024, 0, stream>>>(cur, b1, a2, 800, 5, ACT_ELU, (uint4*)nxt);
    }

    // ---- FC + log_softmax ----
    fc_dot<<<1000, 256, 0, stream>>>(b1, Wfc, bfc, logits);
    lsm<<<1, 1024, 0, stream>>>(logits, (float*)d_out);
}

// Round 29
// 594.287 us; speedup vs baseline: 4.6105x; 1.0363x over previous
//
#include <hip/hip_runtime.h>
#include <math.h>

typedef unsigned int u32;
typedef unsigned long long u64;

#define STRIDE 262656          // per-column stride in floats
#define KSHIFT 19
#define KROUND 0x40000u
#define BAND   384             // 24 exponents x 16 mantissa steps per sign
#define NB     768             // bins per column
#define PA19   0x710u
#define NA19   0x1770u
#define NCOLS  16
#define ZW     (NB*NCOLS)      // u32 words in one bin buffer
#define ACT_PRELU 0
#define ACT_RELU  1
#define ACT_ELU   2

__device__ __forceinline__ float k2f(u32 k){
    u32 u = (k & 0x80000000u) ? k : (k ^ 0x7FFFFFFFu);
    return __uint_as_float(u);
}
__device__ __forceinline__ int bin_of(float v){
    float av = fabsf(v);
    av = fminf(fmaxf(av, 0.00390625f), 65535.96875f);
    u32 u = __float_as_uint(av);
    if (v < 0.f){
        u32 k = 0x80000000u | u;
        int b = (int)(((k + KROUND) >> KSHIFT) - NA19);
        b = b < 0 ? 0 : (b > BAND-1 ? BAND-1 : b);
        return BAND + b;
    } else {
        u32 k = u ^ 0x7FFFFFFFu;
        int b = (int)(((k + KROUND) >> KSHIFT) - PA19);
        b = b < 0 ? 0 : (b > BAND-1 ? BAND-1 : b);
        return b;
    }
}
__device__ __forceinline__ float bin_val(int bin){
    u32 k19 = (bin < BAND) ? ((u32)bin + PA19) : ((u32)(bin - BAND) + NA19);
    return k2f(k19 << KSHIFT);
}

// wave run-length dedup -> one GLOBAL atomic per run per wave
__device__ __forceinline__ void hist_add(u32* __restrict__ Hc, int bin, bool valid, int lane){
    u32 bn = valid ? (u32)bin : 0xFFFFFFFFu;
    u32 prev = __shfl_up(bn, 1);
    bool diff = (lane == 0) || (prev != bn);
    u64 m = __ballot(diff || !valid);
    if (valid && diff){
        u64 above = m & ~((2ull << lane) - 1ull);
        int nxt = above ? (__ffsll((unsigned long long)above) - 1) : 64;
        atomicAdd(&Hc[bin], (u32)(nxt - lane));
    }
}

// wave run-length dedup -> one packed-u16 LDS atomic per run per wave
__device__ __forceinline__ void lds_hist_dedup(u32* __restrict__ hist, int bin, bool valid, int lane){
    u32 bn = valid ? (u32)bin : 0xFFFFFFFFu;
    u32 prev = __shfl_up(bn, 1);
    bool diff = (lane == 0) || (prev != bn);
    u64 m = __ballot(diff || !valid);
    if (valid && diff){
        u64 above = m & ~((2ull << lane) - 1ull);
        int nxt = above ? (__ffsll((unsigned long long)above) - 1) : 64;
        u32 cnt = (u32)(nxt - lane);
        atomicAdd(&hist[bin >> 1], cnt << ((bin & 1) * 16));
    }
}

// ---------------- fold+transpose x -> fx[8][STRIDE]; also zero bin0 ----------------
__global__ __launch_bounds__(256) void foldx(const float* __restrict__ x, float* __restrict__ fx,
                                             uint4* __restrict__ zb)
{
    __shared__ float4 tile[1024];    // 256 rows x 16 floats
    const int tid = threadIdx.x;
    const int h0 = blockIdx.x * 256;
    for (int i = tid; i < 1024; i += 256) tile[i] = ((const float4*)x)[(size_t)h0*4 + i];
    __syncthreads();
    float4 a = tile[tid*4+0], b = tile[tid*4+1], c = tile[tid*4+2], d = tile[tid*4+3];
    const int h = h0 + tid;
    fx[(size_t)0*STRIDE + h] = a.x + a.y;
    fx[(size_t)1*STRIDE + h] = a.z + a.w;
    fx[(size_t)2*STRIDE + h] = b.x + b.y;
    fx[(size_t)3*STRIDE + h] = b.z + b.w;
    fx[(size_t)4*STRIDE + h] = c.x + c.y;
    fx[(size_t)5*STRIDE + h] = c.z + c.w;
    fx[(size_t)6*STRIDE + h] = d.x + d.y;
    fx[(size_t)7*STRIDE + h] = d.z + d.w;
    const uint4 z = make_uint4(0,0,0,0);
    for (int i = blockIdx.x*256 + tid; i < ZW/4; i += gridDim.x*256) zb[i] = z;
}

// ---------------- layer-0 conv+hist: float4 shifted window, 4 outputs/thread ----------------
#define C0CHUNK 8192             // 4 tiles of 2048; 33 chunks x 16 cols = 528 blocks (~2/CU)
__global__ __launch_bounds__(512) void conv0_lds(const float* __restrict__ fx, u32* __restrict__ H,
                                                 const float* __restrict__ w0, const float* __restrict__ b0)
{
    __shared__ u32 hist[NB/2];                 // 1.5 KB packed u16 pairs
    __shared__ __align__(16) float s0f[2148];  // window floats [t0-98, t0+2049]; 537 float4s
    __shared__ float sw[100];                  // sw[99] = 0 pad
    const int colv = blockIdx.y;               // 0..15 = o*8 + wp
    const int o = colv >> 3, wp = colv & 7;
    const int tid = threadIdx.x;
    const int p0 = blockIdx.x * C0CHUNK;
    const int p1 = min(p0 + C0CHUNK, 262242);
    if (p0 >= 262242) return;
    for (int i = tid; i < NB/2; i += 512) hist[i] = 0;
    if (tid < 99) sw[tid] = w0[o*99 + tid];
    if (tid == 99) sw[99] = 0.f;
    const float bias = 2.f * b0[o];            // fold doubles bias
    __syncthreads();
    const float* fc = fx + (size_t)wp * STRIDE;
    const float4* s4 = (const float4*)s0f;
    for (int t0 = p0; t0 < p1; t0 += 2048){
        for (int i = tid; i < 2148; i += 512){
            int h = t0 - 98 + i;
            s0f[i] = (h >= 0 && h < 262144) ? fc[h] : 0.f;
        }
        __syncthreads();
        float a0 = bias, a1 = bias, a2 = bias, a3 = bias;
        float4 c = s4[tid];
        #pragma unroll
        for (int jb = 0; jb < 25; jb++){
            float4 n = s4[tid + jb + 1];
            float w0_ = sw[4*jb+0], w1_ = sw[4*jb+1], w2_ = sw[4*jb+2], w3_ = sw[4*jb+3];
            a0 += w0_*c.x; a1 += w0_*c.y; a2 += w0_*c.z; a3 += w0_*c.w;
            a0 += w1_*c.y; a1 += w1_*c.z; a2 += w1_*c.w; a3 += w1_*n.x;
            a0 += w2_*c.z; a1 += w2_*c.w; a2 += w2_*n.x; a3 += w2_*n.y;
            a0 += w3_*c.w; a1 += w3_*n.x; a2 += w3_*n.y; a3 += w3_*n.z;   // sw[99]=0
            c = n;
        }
        int hp = t0 + tid*4;
        if (hp     < p1){ int b = bin_of(a0); atomicAdd(&hist[b>>1], 1u << ((b&1)*16)); }
        if (hp + 1 < p1){ int b = bin_of(a1); atomicAdd(&hist[b>>1], 1u << ((b&1)*16)); }
        if (hp + 2 < p1){ int b = bin_of(a2); atomicAdd(&hist[b>>1], 1u << ((b&1)*16)); }
        if (hp + 3 < p1){ int b = bin_of(a3); atomicAdd(&hist[b>>1], 1u << ((b&1)*16)); }
        __syncthreads();
    }
    u32* Hc = H + (size_t)colv * NB;
    for (int i = tid; i < NB/2; i += 512){
        u32 w = hist[i];
        if (w){
            u32 lo = w & 0xFFFFu, hi = w >> 16;
            if (lo) atomicAdd(&Hc[2*i],   lo);
            if (hi) atomicAdd(&Hc[2*i+1], hi);
        }
    }
}

// ---------------- K=9 conv+hist: float4 shifted window, 4 outputs/thread ----------------
#define C9CHUNK 8192             // 4 tiles of 2048 per block
template<int FOLDIN>
__global__ __launch_bounds__(512) void conv9_lds(
    const float* __restrict__ In, u32* __restrict__ H,
    const float* __restrict__ Wt, const float* __restrict__ Bs,
    int Hin, int Hout, int Wi, int Wo, float bscale)
{
    __shared__ u32 hist[NB/2];                 // 1.5 KB
    __shared__ __align__(16) float s0f[2056];  // window: logical float i = h - (t0-8), i in [0,2056)
    __shared__ __align__(16) float s1f[2056];
    const int colv = blockIdx.y;               // o*Wo + wp
    const int o = colv / Wo, wp = colv % Wo;
    const int tid = threadIdx.x;
    const int lane = tid & 63;
    const int p0 = blockIdx.x * C9CHUNK;
    const int p1 = min(p0 + C9CHUNK, Hout);
    if (p0 >= Hout) return;
    for (int i = tid; i < NB/2; i += 512) hist[i] = 0;
    float w0r[9], w1r[9];
    #pragma unroll
    for (int j = 0; j < 9; j++){ w0r[j] = Wt[(o*2)*9 + j]; w1r[j] = Wt[(o*2)*9 + 9 + j]; }
    const float bv = bscale * Bs[o];
    __syncthreads();
    const float* i00 = In + (size_t)(0*Wi + (FOLDIN ? 2*wp   : wp))*STRIDE;
    const float* i01 = In + (size_t)(0*Wi + (FOLDIN ? 2*wp+1 : wp))*STRIDE;
    const float* i10 = In + (size_t)(1*Wi + (FOLDIN ? 2*wp   : wp))*STRIDE;
    const float* i11 = In + (size_t)(1*Wi + (FOLDIN ? 2*wp+1 : wp))*STRIDE;
    const float4* s40 = (const float4*)s0f;
    const float4* s41 = (const float4*)s1f;
    for (int t0 = p0; t0 < p1; t0 += 2048){
        for (int i = tid; i < 2056; i += 512){
            int h = t0 - 8 + i;
            float v0 = 0.f, v1 = 0.f;
            if (h >= 0 && h < Hin){
                v0 = FOLDIN ? (i00[h] + i01[h]) : i00[h];
                v1 = FOLDIN ? (i10[h] + i11[h]) : i10[h];
            }
            s0f[i] = v0; s1f[i] = v1;
        }
        __syncthreads();
        // outputs hp = t0 + 4*tid + r (r=0..3); tap j reads logical float 4*tid + r + j
        float a0 = bv, a1 = bv, a2 = bv, a3 = bv;
        {   // channel 0 taps j=0..8 ascending (preserve original accumulation order)
            float4 X = s40[tid], Y = s40[tid+1], Z = s40[tid+2];
            a0 += w0r[0]*X.x; a1 += w0r[0]*X.y; a2 += w0r[0]*X.z; a3 += w0r[0]*X.w;
            a0 += w0r[1]*X.y; a1 += w0r[1]*X.z; a2 += w0r[1]*X.w; a3 += w0r[1]*Y.x;
            a0 += w0r[2]*X.z; a1 += w0r[2]*X.w; a2 += w0r[2]*Y.x; a3 += w0r[2]*Y.y;
            a0 += w0r[3]*X.w; a1 += w0r[3]*Y.x; a2 += w0r[3]*Y.y; a3 += w0r[3]*Y.z;
            a0 += w0r[4]*Y.x; a1 += w0r[4]*Y.y; a2 += w0r[4]*Y.z; a3 += w0r[4]*Y.w;
            a0 += w0r[5]*Y.y; a1 += w0r[5]*Y.z; a2 += w0r[5]*Y.w; a3 += w0r[5]*Z.x;
            a0 += w0r[6]*Y.z; a1 += w0r[6]*Y.w; a2 += w0r[6]*Z.x; a3 += w0r[6]*Z.y;
            a0 += w0r[7]*Y.w; a1 += w0r[7]*Z.x; a2 += w0r[7]*Z.y; a3 += w0r[7]*Z.z;
            a0 += w0r[8]*Z.x; a1 += w0r[8]*Z.y; a2 += w0r[8]*Z.z; a3 += w0r[8]*Z.w;
        }
        {   // then channel 1
            float4 X = s41[tid], Y = s41[tid+1], Z = s41[tid+2];
            a0 += w1r[0]*X.x; a1 += w1r[0]*X.y; a2 += w1r[0]*X.z; a3 += w1r[0]*X.w;
            a0 += w1r[1]*X.y; a1 += w1r[1]*X.z; a2 += w1r[1]*X.w; a3 += w1r[1]*Y.x;
            a0 += w1r[2]*X.z; a1 += w1r[2]*X.w; a2 += w1r[2]*Y.x; a3 += w1r[2]*Y.y;
            a0 += w1r[3]*X.w; a1 += w1r[3]*Y.x; a2 += w1r[3]*Y.y; a3 += w1r[3]*Y.z;
            a0 += w1r[4]*Y.x; a1 += w1r[4]*Y.y; a2 += w1r[4]*Y.z; a3 += w1r[4]*Y.w;
            a0 += w1r[5]*Y.y; a1 += w1r[5]*Y.z; a2 += w1r[5]*Y.w; a3 += w1r[5]*Z.x;
            a0 += w1r[6]*Y.z; a1 += w1r[6]*Y.w; a2 += w1r[6]*Z.x; a3 += w1r[6]*Z.y;
            a0 += w1r[7]*Y.w; a1 += w1r[7]*Z.x; a2 += w1r[7]*Z.y; a3 += w1r[7]*Z.z;
            a0 += w1r[8]*Z.x; a1 += w1r[8]*Z.y; a2 += w1r[8]*Z.z; a3 += w1r[8]*Z.w;
        }
        int hp = t0 + tid*4;
        lds_hist_dedup(hist, bin_of(a0), hp     < p1, lane);
        lds_hist_dedup(hist, bin_of(a1), hp + 1 < p1, lane);
        lds_hist_dedup(hist, bin_of(a2), hp + 2 < p1, lane);
        lds_hist_dedup(hist, bin_of(a3), hp + 3 < p1, lane);
        __syncthreads();
    }
    u32* Hc = H + (size_t)colv * NB;
    for (int i = tid; i < NB/2; i += 512){
        u32 w = hist[i];
        if (w){
            u32 lo = w & 0xFFFFu, hi = w >> 16;
            if (lo) atomicAdd(&Hc[2*i],   lo);
            if (hi) atomicAdd(&Hc[2*i+1], hi);
        }
    }
}

// ---------------- layer-19 conv+hist (K=358, 2->5ch; global dedup atomics) ----------------
template<int INC, int OUTC>
__global__ __launch_bounds__(256) void conv_hist_t(
    const float* __restrict__ In, u32* __restrict__ H,
    const float* __restrict__ Wt, const float* __restrict__ Bs,
    int Hin, int Hout, int K, int pad, int Wi, int Wo, int foldIn, float bscale)
{
    __shared__ float sIn[INC][613];
    __shared__ float sW[OUTC*INC*358];
    const int wp = blockIdx.y;
    const int h0 = blockIdx.x * 256;
    const int tid = threadIdx.x;
    const int lane = tid & 63;
    const int tl = 256 + K - 1;
    for (int t = tid; t < INC*tl; t += 256){
        int c = t / tl, r = t - c*tl;
        int h = h0 - pad + r;
        float v = 0.f;
        if (h >= 0 && h < Hin){
            if (foldIn) v = In[(size_t)(c*Wi + 2*wp)*STRIDE + h] + In[(size_t)(c*Wi + 2*wp + 1)*STRIDE + h];
            else        v = In[(size_t)(c*Wi + wp)*STRIDE + h];
        }
        sIn[c][r] = v;
    }
    for (int t = tid; t < OUTC*INC*K; t += 256) sW[t] = Wt[t];
    __syncthreads();
    int hp = h0 + tid;
    bool valid = (hp < Hout);
    float acc[OUTC];
    #pragma unroll
    for (int o = 0; o < OUTC; o++) acc[o] = bscale * Bs[o];
    for (int c = 0; c < INC; c++){
        for (int j = 0; j < K; j++){
            float xv = sIn[c][tid + j];
            #pragma unroll
            for (int o = 0; o < OUTC; o++) acc[o] += sW[(o*INC + c)*K + j] * xv;
        }
    }
    #pragma unroll
    for (int o = 0; o < OUTC; o++)
        hist_add(H + (size_t)(o*Wo + wp)*NB, bin_of(acc[o]), valid, lane);
}

// ---------------- fused scan + reconstruct (binary search PER RUN) + next-bin zeroing ----------------
__global__ __launch_bounds__(1024) void scan_fill(
    const u32* __restrict__ H, float* __restrict__ dst, const float* __restrict__ alphaPtr,
    int kOut, int dup, int act, uint4* __restrict__ zb)
{
    __shared__ u32 pre[NB];          // 3 KB inclusive prefix
    __shared__ u32 warr[16];
    const int col = blockIdx.y;
    const int tid = threadIdx.x;
    const int lane = tid & 63, wv = tid >> 6;
    const u32* Hc = H + (size_t)col * NB;
    // one bin per thread (tid < 768)
    u32 s = (tid < NB) ? Hc[tid] : 0u;
    u32 ss = s;
    #pragma unroll
    for (int d = 1; d < 64; d <<= 1){
        u32 t = __shfl_up(ss, d);
        if (lane >= d) ss += t;
    }
    if (lane == 63) warr[wv] = ss;
    __syncthreads();
    u32 wb = 0;
    #pragma unroll
    for (int w = 0; w < 16; w++) wb += (w < wv) ? warr[w] : 0u;
    if (tid < NB) pre[tid] = wb + ss;            // inclusive prefix
    __syncthreads();

    const int S  = gridDim.x;
    const int nr = kOut / dup;
    const int per = (nr + S*1024 - 1) / (S*1024);
    int i = (blockIdx.x*1024 + tid) * per;
    const int i1 = min(i + per, nr);
    float* d = dst + (size_t)col * STRIDE;
    const float alpha = alphaPtr[0];
    int lo0 = 0;                                  // monotone lower bound across runs
    while (i < i1){
        int lo = lo0, hi = NB - 1;                // smallest bin with pre[bin] > i
        while (lo < hi){ int m = (lo + hi) >> 1; if (pre[m] > (u32)i) hi = m; else lo = m + 1; }
        float vv = bin_val(lo);
        if (act == ACT_PRELU)      vv = (vv >= 0.f) ? vv : alpha * vv;
        else if (act == ACT_RELU)  vv = (vv > 0.f) ? vv : 0.f;
        else                       vv = (vv > 0.f) ? vv : expm1f(vv);
        int e = (int)min((u32)i1, pre[lo]);
        for (; i < e; i++){
            int bse = i * dup;
            for (int dd = 0; dd < dup; dd++) d[bse + dd] = vv;
        }
        lo0 = lo + 1;                             // next rank's bin is strictly above lo
    }
    // zero the other bin buffer for the next layer (vectorized)
    const uint4 z = make_uint4(0,0,0,0);
    int lin = (blockIdx.y * gridDim.x + blockIdx.x) * 1024 + tid;
    int tot = gridDim.x * gridDim.y * 1024;
    for (int q = lin; q < ZW/4; q += tot) zb[q] = z;
}

// ---------------- FC: 1000 logits, one block each; then log_softmax ----------------
__global__ __launch_bounds__(256) void fc_dot(const float* __restrict__ A, const float* __restrict__ Wfc,
                                              const float* __restrict__ bfc, float* __restrict__ logits)
{
    const int t = blockIdx.x;            // 0..999
    const int o = t / 200, j = t - o*200;
    const float* wrow = Wfc + (size_t)j*1600;
    float acc = 0.f;
    for (int q = threadIdx.x; q < 1600; q += 256){
        int p = q >> 1, wq = q & 1;
        acc += wrow[q] * A[(size_t)(o*2 + wq)*STRIDE + p];
    }
    __shared__ float red[256];
    red[threadIdx.x] = acc;
    __syncthreads();
    for (int s = 128; s > 0; s >>= 1){
        if (threadIdx.x < s) red[threadIdx.x] += red[threadIdx.x + s];
        __syncthreads();
    }
    if (threadIdx.x == 0) logits[t] = red[0] + bfc[j];
}

__global__ __launch_bounds__(1024) void lsm(const float* __restrict__ logits, float* __restrict__ out)
{
    const int tid = threadIdx.x;
    __shared__ float red[1024];
    float lg = (tid < 1000) ? logits[tid] : -INFINITY;
    red[tid] = lg;
    __syncthreads();
    for (int s = 512; s > 0; s >>= 1){
        if (tid < s) red[tid] = fmaxf(red[tid], red[tid + s]);
        __syncthreads();
    }
    float m = red[0];
    __syncthreads();
    red[tid] = (tid < 1000) ? expf(lg - m) : 0.f;
    __syncthreads();
    for (int s = 512; s > 0; s >>= 1){
        if (tid < s) red[tid] += red[tid + s];
        __syncthreads();
    }
    float lse = logf(red[0]);
    if (tid < 1000) out[tid] = lg - m - lse;
}

extern "C" void kernel_launch(void* const* d_in, const int* in_sizes, int n_in,
                              void* d_out, int out_size, void* d_ws, size_t ws_size,
                              hipStream_t stream)
{
    (void)in_sizes; (void)n_in; (void)out_size;
    const size_t need = (size_t)24*STRIDE*4 + (size_t)2*ZW*4 + 4096;
    if (ws_size < need) return;

    const float* x   = (const float*)d_in[0];
    const float* w0  = (const float*)d_in[1];
    const float* b0  = (const float*)d_in[2];
    const float* wm  = (const float*)d_in[3];
    const float* bm  = (const float*)d_in[4];
    const float* w18 = (const float*)d_in[5];
    const float* b18 = (const float*)d_in[6];
    const float* w19 = (const float*)d_in[7];
    const float* b19 = (const float*)d_in[8];
    const float* a1  = (const float*)d_in[9];
    const float* a2  = (const float*)d_in[10];
    const float* Wfc = (const float*)d_in[11];
    const float* bfc = (const float*)d_in[12];

    float* b1   = (float*)d_ws;
    float* fx   = b1 + (size_t)16*STRIDE;
    u32*  bin0  = (u32*)(fx + (size_t)8*STRIDE);
    u32*  bin1  = bin0 + (size_t)ZW;
    float* logits = (float*)(bin1 + (size_t)ZW);

    u32* cur = bin0;
    u32* nxt = bin1;

    // fold+transpose x; zero bin0
    foldx<<<1024, 256, 0, stream>>>(x, fx, (uint4*)cur);

    // ---- layer 0: conv(99, pad 98) -> fold(x2 dup) -> kmax 262144 -> PReLU(a1) ----
    conv0_lds<<<dim3(33, 16), 512, 0, stream>>>(fx, cur, w0, b0);
    scan_fill<<<dim3(16, 16), 1024, 0, stream>>>(cur, b1, a1, 262144, 2, ACT_PRELU, (uint4*)nxt);
    { u32* t = cur; cur = nxt; nxt = t; }
    int Hin = 262144;

    // ---- layers 1..17: conv(9, pad 8) -> kmax -> PReLU(a2)/ReLU ----
    static const int ks[17] = {249036,235929,222822,209715,196608,183500,170393,157286,
                               144179,131072,117964,104857,91750,78643,65536,52428,39321};
    for (int i = 0; i < 17; i++){
        int Hout = Hin + 8;
        int nch = (Hout + C9CHUNK - 1) / C9CHUNK;
        conv9_lds<0><<<dim3(nch, 16), 512, 0, stream>>>(
            b1, cur, wm + (size_t)i*36, bm + (size_t)i*2, Hin, Hout, 8, 8, 1.f);
        scan_fill<<<dim3(16, 16), 1024, 0, stream>>>(cur, b1, a2, ks[i], 1,
                                                     (i == 0) ? ACT_PRELU : ACT_RELU, (uint4*)nxt);
        { u32* t = cur; cur = nxt; nxt = t; }
        Hin = ks[i];
    }

    // ---- layer 18: conv(9) -> fold(widths 8->4, x2 dup) -> kmax 26214 -> ELU ----
    {
        int Hout = Hin + 8;   // 39329
        int nch = (Hout + C9CHUNK - 1) / C9CHUNK;
        conv9_lds<1><<<dim3(nch, 8), 512, 0, stream>>>(
            b1, cur, w18, b18, Hin, Hout, 8, 4, 2.f);
        scan_fill<<<dim3(4, 8), 1024, 0, stream>>>(cur, b1, a2, 26214, 2, ACT_ELU, (uint4*)nxt);
        { u32* t = cur; cur = nxt; nxt = t; }
        Hin = 26214;
    }

    // ---- layer 19: conv(358, pad 357, 2->5ch) -> fold(widths 4->2, x5 dup) -> kmax 800 -> ELU ----
    {
        int Hout = Hin + 714 - 358 + 1;   // 26571
        conv_hist_t<2,5><<<dim3((Hout + 255)/256, 2), 256, 0, stream>>>(
            b1, cur, w19, b19, Hin, Hout, 358, 357, 4, 2, 1, 2.f);
        scan_fill<<<dim3(1, 10), 1024, 0, stream>>>(cur, b1, a2, 800, 5, ACT_ELU, (uint4*)nxt);
    }

    // ---- FC + log_softmax ----
    fc_dot<<<1000, 256, 0, stream>>>(b1, Wfc, bfc, logits);
    lsm<<<1, 1024, 0, stream>>>(logits, (float*)d_out);
}

// Round 30
// 585.843 us; speedup vs baseline: 4.6769x; 1.0144x over previous
//
#include <hip/hip_runtime.h>
#include <math.h>

typedef unsigned int u32;
typedef unsigned long long u64;

#define STRIDE 262656          // per-column stride in floats
#define KSHIFT 20
#define KROUND 0x80000u
#define BAND   192             // 24 exponents x 8 mantissa steps per sign
#define NB     384             // bins per column
#define PA20   0x388u
#define NA20   0xBB8u
#define NCOLS  16
#define ZW     (NB*NCOLS)      // u32 words in one bin buffer
#define ACT_PRELU 0
#define ACT_RELU  1
#define ACT_ELU   2

__device__ __forceinline__ float k2f(u32 k){
    u32 u = (k & 0x80000000u) ? k : (k ^ 0x7FFFFFFFu);
    return __uint_as_float(u);
}
__device__ __forceinline__ int bin_of(float v){
    float av = fabsf(v);
    av = fminf(fmaxf(av, 0.00390625f), 65535.96875f);
    u32 u = __float_as_uint(av);
    if (v < 0.f){
        u32 k = 0x80000000u | u;
        int b = (int)(((k + KROUND) >> KSHIFT) - NA20);
        b = b < 0 ? 0 : (b > BAND-1 ? BAND-1 : b);
        return BAND + b;
    } else {
        u32 k = u ^ 0x7FFFFFFFu;
        int b = (int)(((k + KROUND) >> KSHIFT) - PA20);
        b = b < 0 ? 0 : (b > BAND-1 ? BAND-1 : b);
        return b;
    }
}
__device__ __forceinline__ float bin_val(int bin){
    u32 k20 = (bin < BAND) ? ((u32)bin + PA20) : ((u32)(bin - BAND) + NA20);
    return k2f(k20 << KSHIFT);
}

// wave run-length dedup -> one GLOBAL atomic per run per wave
__device__ __forceinline__ void hist_add(u32* __restrict__ Hc, int bin, bool valid, int lane){
    u32 bn = valid ? (u32)bin : 0xFFFFFFFFu;
    u32 prev = __shfl_up(bn, 1);
    bool diff = (lane == 0) || (prev != bn);
    u64 m = __ballot(diff || !valid);
    if (valid && diff){
        u64 above = m & ~((2ull << lane) - 1ull);
        int nxt = above ? (__ffsll((unsigned long long)above) - 1) : 64;
        atomicAdd(&Hc[bin], (u32)(nxt - lane));
    }
}

// wave run-length dedup -> one packed-u16 LDS atomic per run per wave
__device__ __forceinline__ void lds_hist_dedup(u32* __restrict__ hist, int bin, bool valid, int lane){
    u32 bn = valid ? (u32)bin : 0xFFFFFFFFu;
    u32 prev = __shfl_up(bn, 1);
    bool diff = (lane == 0) || (prev != bn);
    u64 m = __ballot(diff || !valid);
    if (valid && diff){
        u64 above = m & ~((2ull << lane) - 1ull);
        int nxt = above ? (__ffsll((unsigned long long)above) - 1) : 64;
        u32 cnt = (u32)(nxt - lane);
        atomicAdd(&hist[bin >> 1], cnt << ((bin & 1) * 16));
    }
}

// ---------------- fold+transpose x -> fx[8][STRIDE]; also zero bin0 ----------------
__global__ __launch_bounds__(256) void foldx(const float* __restrict__ x, float* __restrict__ fx,
                                             uint4* __restrict__ zb)
{
    __shared__ float4 tile[1024];    // 256 rows x 16 floats
    const int tid = threadIdx.x;
    const int h0 = blockIdx.x * 256;
    for (int i = tid; i < 1024; i += 256) tile[i] = ((const float4*)x)[(size_t)h0*4 + i];
    __syncthreads();
    float4 a = tile[tid*4+0], b = tile[tid*4+1], c = tile[tid*4+2], d = tile[tid*4+3];
    const int h = h0 + tid;
    fx[(size_t)0*STRIDE + h] = a.x + a.y;
    fx[(size_t)1*STRIDE + h] = a.z + a.w;
    fx[(size_t)2*STRIDE + h] = b.x + b.y;
    fx[(size_t)3*STRIDE + h] = b.z + b.w;
    fx[(size_t)4*STRIDE + h] = c.x + c.y;
    fx[(size_t)5*STRIDE + h] = c.z + c.w;
    fx[(size_t)6*STRIDE + h] = d.x + d.y;
    fx[(size_t)7*STRIDE + h] = d.z + d.w;
    const uint4 z = make_uint4(0,0,0,0);
    for (int i = blockIdx.x*256 + tid; i < ZW/4; i += gridDim.x*256) zb[i] = z;
}

// ---------------- layer-0 conv+hist: float4 shifted window, 4 outputs/thread ----------------
#define C0CHUNK 8192             // 4 tiles of 2048; 33 chunks x 16 cols = 528 blocks (~2/CU)
__global__ __launch_bounds__(512) void conv0_lds(const float* __restrict__ fx, u32* __restrict__ H,
                                                 const float* __restrict__ w0, const float* __restrict__ b0)
{
    __shared__ u32 hist[NB/2];                 // 0.75 KB packed u16 pairs
    __shared__ __align__(16) float s0f[2148];  // window floats [t0-98, t0+2049]; 537 float4s
    __shared__ float sw[100];                  // sw[99] = 0 pad
    const int colv = blockIdx.y;               // 0..15 = o*8 + wp
    const int o = colv >> 3, wp = colv & 7;
    const int tid = threadIdx.x;
    const int p0 = blockIdx.x * C0CHUNK;
    const int p1 = min(p0 + C0CHUNK, 262242);
    if (p0 >= 262242) return;
    for (int i = tid; i < NB/2; i += 512) hist[i] = 0;
    if (tid < 99) sw[tid] = w0[o*99 + tid];
    if (tid == 99) sw[99] = 0.f;
    const float bias = 2.f * b0[o];            // fold doubles bias
    __syncthreads();
    const float* fc = fx + (size_t)wp * STRIDE;
    const float4* s4 = (const float4*)s0f;
    for (int t0 = p0; t0 < p1; t0 += 2048){
        for (int i = tid; i < 2148; i += 512){
            int h = t0 - 98 + i;
            s0f[i] = (h >= 0 && h < 262144) ? fc[h] : 0.f;
        }
        __syncthreads();
        float a0 = bias, a1 = bias, a2 = bias, a3 = bias;
        float4 c = s4[tid];
        #pragma unroll
        for (int jb = 0; jb < 25; jb++){
            float4 n = s4[tid + jb + 1];
            float w0_ = sw[4*jb+0], w1_ = sw[4*jb+1], w2_ = sw[4*jb+2], w3_ = sw[4*jb+3];
            a0 += w0_*c.x; a1 += w0_*c.y; a2 += w0_*c.z; a3 += w0_*c.w;
            a0 += w1_*c.y; a1 += w1_*c.z; a2 += w1_*c.w; a3 += w1_*n.x;
            a0 += w2_*c.z; a1 += w2_*c.w; a2 += w2_*n.x; a3 += w2_*n.y;
            a0 += w3_*c.w; a1 += w3_*n.x; a2 += w3_*n.y; a3 += w3_*n.z;   // sw[99]=0
            c = n;
        }
        int hp = t0 + tid*4;
        if (hp     < p1){ int b = bin_of(a0); atomicAdd(&hist[b>>1], 1u << ((b&1)*16)); }
        if (hp + 1 < p1){ int b = bin_of(a1); atomicAdd(&hist[b>>1], 1u << ((b&1)*16)); }
        if (hp + 2 < p1){ int b = bin_of(a2); atomicAdd(&hist[b>>1], 1u << ((b&1)*16)); }
        if (hp + 3 < p1){ int b = bin_of(a3); atomicAdd(&hist[b>>1], 1u << ((b&1)*16)); }
        __syncthreads();
    }
    u32* Hc = H + (size_t)colv * NB;
    for (int i = tid; i < NB/2; i += 512){
        u32 w = hist[i];
        if (w){
            u32 lo = w & 0xFFFFu, hi = w >> 16;
            if (lo) atomicAdd(&Hc[2*i],   lo);
            if (hi) atomicAdd(&Hc[2*i+1], hi);
        }
    }
}

// ---------------- K=9 conv+hist: float4 shifted window, 4 outputs/thread ----------------
#define C9CHUNK 8192             // 4 tiles of 2048 per block
template<int FOLDIN>
__global__ __launch_bounds__(512) void conv9_lds(
    const float* __restrict__ In, u32* __restrict__ H,
    const float* __restrict__ Wt, const float* __restrict__ Bs,
    int Hin, int Hout, int Wi, int Wo, float bscale)
{
    __shared__ u32 hist[NB/2];                 // 0.75 KB
    __shared__ __align__(16) float s0f[2056];  // window: logical float i = h - (t0-8), i in [0,2056)
    __shared__ __align__(16) float s1f[2056];
    const int colv = blockIdx.y;               // o*Wo + wp
    const int o = colv / Wo, wp = colv % Wo;
    const int tid = threadIdx.x;
    const int lane = tid & 63;
    const int p0 = blockIdx.x * C9CHUNK;
    const int p1 = min(p0 + C9CHUNK, Hout);
    if (p0 >= Hout) return;
    for (int i = tid; i < NB/2; i += 512) hist[i] = 0;
    float w0r[9], w1r[9];
    #pragma unroll
    for (int j = 0; j < 9; j++){ w0r[j] = Wt[(o*2)*9 + j]; w1r[j] = Wt[(o*2)*9 + 9 + j]; }
    const float bv = bscale * Bs[o];
    __syncthreads();
    const float* i00 = In + (size_t)(0*Wi + (FOLDIN ? 2*wp   : wp))*STRIDE;
    const float* i01 = In + (size_t)(0*Wi + (FOLDIN ? 2*wp+1 : wp))*STRIDE;
    const float* i10 = In + (size_t)(1*Wi + (FOLDIN ? 2*wp   : wp))*STRIDE;
    const float* i11 = In + (size_t)(1*Wi + (FOLDIN ? 2*wp+1 : wp))*STRIDE;
    const float4* s40 = (const float4*)s0f;
    const float4* s41 = (const float4*)s1f;
    for (int t0 = p0; t0 < p1; t0 += 2048){
        for (int i = tid; i < 2056; i += 512){
            int h = t0 - 8 + i;
            float v0 = 0.f, v1 = 0.f;
            if (h >= 0 && h < Hin){
                v0 = FOLDIN ? (i00[h] + i01[h]) : i00[h];
                v1 = FOLDIN ? (i10[h] + i11[h]) : i10[h];
            }
            s0f[i] = v0; s1f[i] = v1;
        }
        __syncthreads();
        // outputs hp = t0 + 4*tid + r (r=0..3); tap j reads logical float 4*tid + r + j
        float a0 = bv, a1 = bv, a2 = bv, a3 = bv;
        {   // channel 0 taps j=0..8 ascending (preserve original accumulation order)
            float4 X = s40[tid], Y = s40[tid+1], Z = s40[tid+2];
            a0 += w0r[0]*X.x; a1 += w0r[0]*X.y; a2 += w0r[0]*X.z; a3 += w0r[0]*X.w;
            a0 += w0r[1]*X.y; a1 += w0r[1]*X.z; a2 += w0r[1]*X.w; a3 += w0r[1]*Y.x;
            a0 += w0r[2]*X.z; a1 += w0r[2]*X.w; a2 += w0r[2]*Y.x; a3 += w0r[2]*Y.y;
            a0 += w0r[3]*X.w; a1 += w0r[3]*Y.x; a2 += w0r[3]*Y.y; a3 += w0r[3]*Y.z;
            a0 += w0r[4]*Y.x; a1 += w0r[4]*Y.y; a2 += w0r[4]*Y.z; a3 += w0r[4]*Y.w;
            a0 += w0r[5]*Y.y; a1 += w0r[5]*Y.z; a2 += w0r[5]*Y.w; a3 += w0r[5]*Z.x;
            a0 += w0r[6]*Y.z; a1 += w0r[6]*Y.w; a2 += w0r[6]*Z.x; a3 += w0r[6]*Z.y;
            a0 += w0r[7]*Y.w; a1 += w0r[7]*Z.x; a2 += w0r[7]*Z.y; a3 += w0r[7]*Z.z;
            a0 += w0r[8]*Z.x; a1 += w0r[8]*Z.y; a2 += w0r[8]*Z.z; a3 += w0r[8]*Z.w;
        }
        {   // then channel 1
            float4 X = s41[tid], Y = s41[tid+1], Z = s41[tid+2];
            a0 += w1r[0]*X.x; a1 += w1r[0]*X.y; a2 += w1r[0]*X.z; a3 += w1r[0]*X.w;
            a0 += w1r[1]*X.y; a1 += w1r[1]*X.z; a2 += w1r[1]*X.w; a3 += w1r[1]*Y.x;
            a0 += w1r[2]*X.z; a1 += w1r[2]*X.w; a2 += w1r[2]*Y.x; a3 += w1r[2]*Y.y;
            a0 += w1r[3]*X.w; a1 += w1r[3]*Y.x; a2 += w1r[3]*Y.y; a3 += w1r[3]*Y.z;
            a0 += w1r[4]*Y.x; a1 += w1r[4]*Y.y; a2 += w1r[4]*Y.z; a3 += w1r[4]*Y.w;
            a0 += w1r[5]*Y.y; a1 += w1r[5]*Y.z; a2 += w1r[5]*Y.w; a3 += w1r[5]*Z.x;
            a0 += w1r[6]*Y.z; a1 += w1r[6]*Y.w; a2 += w1r[6]*Z.x; a3 += w1r[6]*Z.y;
            a0 += w1r[7]*Y.w; a1 += w1r[7]*Z.x; a2 += w1r[7]*Z.y; a3 += w1r[7]*Z.z;
            a0 += w1r[8]*Z.x; a1 += w1r[8]*Z.y; a2 += w1r[8]*Z.z; a3 += w1r[8]*Z.w;
        }
        int hp = t0 + tid*4;
        lds_hist_dedup(hist, bin_of(a0), hp     < p1, lane);
        lds_hist_dedup(hist, bin_of(a1), hp + 1 < p1, lane);
        lds_hist_dedup(hist, bin_of(a2), hp + 2 < p1, lane);
        lds_hist_dedup(hist, bin_of(a3), hp + 3 < p1, lane);
        __syncthreads();
    }
    u32* Hc = H + (size_t)colv * NB;
    for (int i = tid; i < NB/2; i += 512){
        u32 w = hist[i];
        if (w){
            u32 lo = w & 0xFFFFu, hi = w >> 16;
            if (lo) atomicAdd(&Hc[2*i],   lo);
            if (hi) atomicAdd(&Hc[2*i+1], hi);
        }
    }
}

// ---------------- layer-19 conv+hist (K=358, 2->5ch; global dedup atomics) ----------------
template<int INC, int OUTC>
__global__ __launch_bounds__(256) void conv_hist_t(
    const float* __restrict__ In, u32* __restrict__ H,
    const float* __restrict__ Wt, const float* __restrict__ Bs,
    int Hin, int Hout, int K, int pad, int Wi, int Wo, int foldIn, float bscale)
{
    __shared__ float sIn[INC][613];
    __shared__ float sW[OUTC*INC*358];
    const int wp = blockIdx.y;
    const int h0 = blockIdx.x * 256;
    const int tid = threadIdx.x;
    const int lane = tid & 63;
    const int tl = 256 + K - 1;
    for (int t = tid; t < INC*tl; t += 256){
        int c = t / tl, r = t - c*tl;
        int h = h0 - pad + r;
        float v = 0.f;
        if (h >= 0 && h < Hin){
            if (foldIn) v = In[(size_t)(c*Wi + 2*wp)*STRIDE + h] + In[(size_t)(c*Wi + 2*wp + 1)*STRIDE + h];
            else        v = In[(size_t)(c*Wi + wp)*STRIDE + h];
        }
        sIn[c][r] = v;
    }
    for (int t = tid; t < OUTC*INC*K; t += 256) sW[t] = Wt[t];
    __syncthreads();
    int hp = h0 + tid;
    bool valid = (hp < Hout);
    float acc[OUTC];
    #pragma unroll
    for (int o = 0; o < OUTC; o++) acc[o] = bscale * Bs[o];
    for (int c = 0; c < INC; c++){
        for (int j = 0; j < K; j++){
            float xv = sIn[c][tid + j];
            #pragma unroll
            for (int o = 0; o < OUTC; o++) acc[o] += sW[(o*INC + c)*K + j] * xv;
        }
    }
    #pragma unroll
    for (int o = 0; o < OUTC; o++)
        hist_add(H + (size_t)(o*Wo + wp)*NB, bin_of(acc[o]), valid, lane);
}

// ---------------- fused scan + reconstruct (binary search PER RUN) + next-bin zeroing ----------------
__global__ __launch_bounds__(1024) void scan_fill(
    const u32* __restrict__ H, float* __restrict__ dst, const float* __restrict__ alphaPtr,
    int kOut, int dup, int act, uint4* __restrict__ zb)
{
    __shared__ u32 pre[NB];          // 1.5 KB inclusive prefix
    __shared__ u32 warr[16];
    const int col = blockIdx.y;
    const int tid = threadIdx.x;
    const int lane = tid & 63, wv = tid >> 6;
    const u32* Hc = H + (size_t)col * NB;
    // one bin per thread (tid < 384)
    u32 s = (tid < NB) ? Hc[tid] : 0u;
    u32 ss = s;
    #pragma unroll
    for (int d = 1; d < 64; d <<= 1){
        u32 t = __shfl_up(ss, d);
        if (lane >= d) ss += t;
    }
    if (lane == 63) warr[wv] = ss;
    __syncthreads();
    u32 wb = 0;
    #pragma unroll
    for (int w = 0; w < 16; w++) wb += (w < wv) ? warr[w] : 0u;
    if (tid < NB) pre[tid] = wb + ss;            // inclusive prefix
    __syncthreads();

    const int S  = gridDim.x;
    const int nr = kOut / dup;
    const int per = (nr + S*1024 - 1) / (S*1024);
    int i = (blockIdx.x*1024 + tid) * per;
    const int i1 = min(i + per, nr);
    float* d = dst + (size_t)col * STRIDE;
    const float alpha = alphaPtr[0];
    int lo0 = 0;                                  // monotone lower bound across runs
    while (i < i1){
        int lo = lo0, hi = NB - 1;                // smallest bin with pre[bin] > i
        while (lo < hi){ int m = (lo + hi) >> 1; if (pre[m] > (u32)i) hi = m; else lo = m + 1; }
        float vv = bin_val(lo);
        if (act == ACT_PRELU)      vv = (vv >= 0.f) ? vv : alpha * vv;
        else if (act == ACT_RELU)  vv = (vv > 0.f) ? vv : 0.f;
        else                       vv = (vv > 0.f) ? vv : expm1f(vv);
        int e = (int)min((u32)i1, pre[lo]);
        for (; i < e; i++){
            int bse = i * dup;
            for (int dd = 0; dd < dup; dd++) d[bse + dd] = vv;
        }
        lo0 = lo + 1;                             // next rank's bin is strictly above lo
    }
    // zero the other bin buffer for the next layer (vectorized)
    const uint4 z = make_uint4(0,0,0,0);
    int lin = (blockIdx.y * gridDim.x + blockIdx.x) * 1024 + tid;
    int tot = gridDim.x * gridDim.y * 1024;
    for (int q = lin; q < ZW/4; q += tot) zb[q] = z;
}

// ---------------- FC: 1000 logits, one block each; then log_softmax ----------------
__global__ __launch_bounds__(256) void fc_dot(const float* __restrict__ A, const float* __restrict__ Wfc,
                                              const float* __restrict__ bfc, float* __restrict__ logits)
{
    const int t = blockIdx.x;            // 0..999
    const int o = t / 200, j = t - o*200;
    const float* wrow = Wfc + (size_t)j*1600;
    float acc = 0.f;
    for (int q = threadIdx.x; q < 1600; q += 256){
        int p = q >> 1, wq = q & 1;
        acc += wrow[q] * A[(size_t)(o*2 + wq)*STRIDE + p];
    }
    __shared__ float red[256];
    red[threadIdx.x] = acc;
    __syncthreads();
    for (int s = 128; s > 0; s >>= 1){
        if (threadIdx.x < s) red[threadIdx.x] += red[threadIdx.x + s];
        __syncthreads();
    }
    if (threadIdx.x == 0) logits[t] = red[0] + bfc[j];
}

__global__ __launch_bounds__(1024) void lsm(const float* __restrict__ logits, float* __restrict__ out)
{
    const int tid = threadIdx.x;
    __shared__ float red[1024];
    float lg = (tid < 1000) ? logits[tid] : -INFINITY;
    red[tid] = lg;
    __syncthreads();
    for (int s = 512; s > 0; s >>= 1){
        if (tid < s) red[tid] = fmaxf(red[tid], red[tid + s]);
        __syncthreads();
    }
    float m = red[0];
    __syncthreads();
    red[tid] = (tid < 1000) ? expf(lg - m) : 0.f;
    __syncthreads();
    for (int s = 512; s > 0; s >>= 1){
        if (tid < s) red[tid] += red[tid + s];
        __syncthreads();
    }
    float lse = logf(red[0]);
    if (tid < 1000) out[tid] = lg - m - lse;
}

extern "C" void kernel_launch(void* const* d_in, const int* in_sizes, int n_in,
                              void* d_out, int out_size, void* d_ws, size_t ws_size,
                              hipStream_t stream)
{
    (void)in_sizes; (void)n_in; (void)out_size;
    const size_t need = (size_t)24*STRIDE*4 + (size_t)2*ZW*4 + 4096;
    if (ws_size < need) return;

    const float* x   = (const float*)d_in[0];
    const float* w0  = (const float*)d_in[1];
    const float* b0  = (const float*)d_in[2];
    const float* wm  = (const float*)d_in[3];
    const float* bm  = (const float*)d_in[4];
    const float* w18 = (const float*)d_in[5];
    const float* b18 = (const float*)d_in[6];
    const float* w19 = (const float*)d_in[7];
    const float* b19 = (const float*)d_in[8];
    const float* a1  = (const float*)d_in[9];
    const float* a2  = (const float*)d_in[10];
    const float* Wfc = (const float*)d_in[11];
    const float* bfc = (const float*)d_in[12];

    float* b1   = (float*)d_ws;
    float* fx   = b1 + (size_t)16*STRIDE;
    u32*  bin0  = (u32*)(fx + (size_t)8*STRIDE);
    u32*  bin1  = bin0 + (size_t)ZW;
    float* logits = (float*)(bin1 + (size_t)ZW);

    u32* cur = bin0;
    u32* nxt = bin1;

    // fold+transpose x; zero bin0
    foldx<<<1024, 256, 0, stream>>>(x, fx, (uint4*)cur);

    // ---- layer 0: conv(99, pad 98) -> fold(x2 dup) -> kmax 262144 -> PReLU(a1) ----
    conv0_lds<<<dim3(33, 16), 512, 0, stream>>>(fx, cur, w0, b0);
    scan_fill<<<dim3(16, 16), 1024, 0, stream>>>(cur, b1, a1, 262144, 2, ACT_PRELU, (uint4*)nxt);
    { u32* t = cur; cur = nxt; nxt = t; }
    int Hin = 262144;

    // ---- layers 1..17: conv(9, pad 8) -> kmax -> PReLU(a2)/ReLU ----
    static const int ks[17] = {249036,235929,222822,209715,196608,183500,170393,157286,
                               144179,131072,117964,104857,91750,78643,65536,52428,39321};
    for (int i = 0; i < 17; i++){
        int Hout = Hin + 8;
        int nch = (Hout + C9CHUNK - 1) / C9CHUNK;
        conv9_lds<0><<<dim3(nch, 16), 512, 0, stream>>>(
            b1, cur, wm + (size_t)i*36, bm + (size_t)i*2, Hin, Hout, 8, 8, 1.f);
        scan_fill<<<dim3(16, 16), 1024, 0, stream>>>(cur, b1, a2, ks[i], 1,
                                                     (i == 0) ? ACT_PRELU : ACT_RELU, (uint4*)nxt);
        { u32* t = cur; cur = nxt; nxt = t; }
        Hin = ks[i];
    }

    // ---- layer 18: conv(9) -> fold(widths 8->4, x2 dup) -> kmax 26214 -> ELU ----
    {
        int Hout = Hin + 8;   // 39329
        int nch = (Hout + C9CHUNK - 1) / C9CHUNK;
        conv9_lds<1><<<dim3(nch, 8), 512, 0, stream>>>(
            b1, cur, w18, b18, Hin, Hout, 8, 4, 2.f);
        scan_fill<<<dim3(4, 8), 1024, 0, stream>>>(cur, b1, a2, 26214, 2, ACT_ELU, (uint4*)nxt);
        { u32* t = cur; cur = nxt; nxt = t; }
        Hin = 26214;
    }

    // ---- layer 19: conv(358, pad 357, 2->5ch) -> fold(widths 4->2, x5 dup) -> kmax 800 -> ELU ----
    {
        int Hout = Hin + 714 - 358 + 1;   // 26571
        conv_hist_t<2,5><<<dim3((Hout + 255)/256, 2), 256, 0, stream>>>(
            b1, cur, w19, b19, Hin, Hout, 358, 357, 4, 2, 1, 2.f);
        scan_fill<<<dim3(1, 10), 1024, 0, stream>>>(cur, b1, a2, 800, 5, ACT_ELU, (uint4*)nxt);
    }

    // ---- FC + log_softmax ----
    fc_dot<<<1000, 256, 0, stream>>>(b1, Wfc, bfc, logits);
    lsm<<<1, 1024, 0, stream>>>(logits, (float*)d_out);
}